// Round 1
// baseline (1262.082 us; speedup 1.0000x reference)
//
#include <hip/hip_runtime.h>
#include <cstddef>
#include <cstdint>

// ---------------- problem constants ----------------
constexpr int G      = 8192;        // statement graphs
constexpr int NAST   = 32;          // nodes per AST
constexpr int N0     = G * NAST;    // 262144
constexpr int D_EMB  = 128;
constexpr int C0     = 192;         // 3 * H_IN
constexpr int H_IN   = 64;
constexpr int K0     = 23;          // ceil(0.7*32)
constexpr int N1     = G * K0;      // 188416
constexpr int K1     = 12;          // ceil(0.5*23)
constexpr int ENC    = 128;
constexpr int NSTMT  = 8192;
constexpr int EST    = 32768;
constexpr int HO3    = 384;         // 3 * H_OUT
constexpr int HOUT   = 128;
constexpr int NSEL   = 4096;

// ---------------- GEMM: C[M,N] = A[M,K] @ B[K,N], row-major ----------------
// BM=64, BN=64, BK=16, 256 threads, 4x4 per thread.
// GATHER: A row index via rowmap, element = relu(a * tanh(score[old]))
template<bool GATHER>
__global__ __launch_bounds__(256) void gemm_nn(
    const float* __restrict__ A, const float* __restrict__ B, float* __restrict__ C,
    int M, int N, int K,
    const int* __restrict__ rowmap, const float* __restrict__ score)
{
    __shared__ float As[16][64];
    __shared__ float Bs[16][64];
    int tid = threadIdx.x;
    int bm = blockIdx.x, bn = blockIdx.y;
    int arow = tid >> 2;          // 0..63
    int aks  = (tid & 3) << 2;    // 0,4,8,12
    int brow = tid >> 4;          // 0..15
    int bns  = (tid & 15) << 2;   // 0..60
    int tm = tid >> 4, tn = tid & 15;
    float acc[4][4] = {};

    int grow = bm * 64 + arow;
    const float* arowp;
    float gate = 1.f;
    if (GATHER) {
        int old = rowmap[grow];
        gate = tanhf(score[old]);
        arowp = A + (size_t)old * K;
    } else {
        arowp = A + (size_t)grow * K;
    }

    for (int kt = 0; kt < K; kt += 16) {
        float4 av = *(const float4*)(arowp + kt + aks);
        if (GATHER) {
            av.x = fmaxf(av.x * gate, 0.f); av.y = fmaxf(av.y * gate, 0.f);
            av.z = fmaxf(av.z * gate, 0.f); av.w = fmaxf(av.w * gate, 0.f);
        }
        As[aks + 0][arow] = av.x; As[aks + 1][arow] = av.y;
        As[aks + 2][arow] = av.z; As[aks + 3][arow] = av.w;
        float4 bv = *(const float4*)(B + (size_t)(kt + brow) * N + bn * 64 + bns);
        *(float4*)&Bs[brow][bns] = bv;
        __syncthreads();
        #pragma unroll
        for (int kk = 0; kk < 16; ++kk) {
            float4 a4 = *(const float4*)&As[kk][tm << 2];
            float4 b4 = *(const float4*)&Bs[kk][tn << 2];
            float a_[4] = {a4.x, a4.y, a4.z, a4.w};
            float b_[4] = {b4.x, b4.y, b4.z, b4.w};
            #pragma unroll
            for (int i = 0; i < 4; ++i)
                #pragma unroll
                for (int j = 0; j < 4; ++j)
                    acc[i][j] += a_[i] * b_[j];
        }
        __syncthreads();
    }
    #pragma unroll
    for (int i = 0; i < 4; ++i) {
        int r = bm * 64 + (tm << 2) + i;
        float4 o = {acc[i][0], acc[i][1], acc[i][2], acc[i][3]};
        *(float4*)(C + (size_t)r * N + bn * 64 + (tn << 2)) = o;
    }
}

// ---------------- GAT0 attention (per AST graph, in place) ----------------
// h[N0,192] -> out = attention(self,parent) + bias -> tanh, in place
__global__ __launch_bounds__(256) void gat0_att(
    float* __restrict__ h, const int* __restrict__ ast_src,
    const float* __restrict__ asrc_w, const float* __restrict__ adst_w,
    const float* __restrict__ bias)
{
    __shared__ float hs[NAST * C0];
    __shared__ float as_[NAST][3], ad_[NAST][3];
    __shared__ float aS[NAST][3], aP[NAST][3];
    __shared__ int parl[NAST];
    int g = blockIdx.x, tid = threadIdx.x;
    const float4* src4 = (const float4*)(h + (size_t)g * NAST * C0);
    float4* hs4 = (float4*)hs;
    for (int i = tid; i < NAST * C0 / 4; i += 256) hs4[i] = src4[i];
    if (tid < NAST) parl[tid] = (tid == 0) ? -1 : (ast_src[g * (NAST - 1) + tid - 1] - g * NAST);
    __syncthreads();
    if (tid < NAST * 6) {
        int r = tid / 6, q = tid % 6, hh = q >> 1, sd = q & 1;
        const float* w = (sd ? adst_w : asrc_w) + hh * 64;
        const float* row = hs + r * C0 + hh * 64;
        float acc = 0.f;
        for (int c = 0; c < 64; ++c) acc += row[c] * w[c];
        if (sd) ad_[r][hh] = acc; else as_[r][hh] = acc;
    }
    __syncthreads();
    if (tid < NAST * 3) {
        int r = tid / 3, hh = tid % 3;
        int p = parl[r];
        if (p < 0) { aS[r][hh] = 1.f; aP[r][hh] = 0.f; }
        else {
            float ls = as_[r][hh] + ad_[r][hh]; ls = ls > 0 ? ls : 0.2f * ls;
            float lp = as_[p][hh] + ad_[r][hh]; lp = lp > 0 ? lp : 0.2f * lp;
            float m = fmaxf(ls, lp);
            float es = expf(ls - m), ep = expf(lp - m);
            float inv = 1.f / (es + ep);
            aS[r][hh] = es * inv; aP[r][hh] = ep * inv;
        }
    }
    __syncthreads();
    for (int i = tid; i < NAST * C0; i += 256) {
        int r = i / C0, j = i % C0, hh = j >> 6;
        int p = parl[r];
        float v = aS[r][hh] * hs[r * C0 + j];
        if (p >= 0) v += aP[r][hh] * hs[p * C0 + j];
        h[(size_t)g * NAST * C0 + i] = tanhf(v + bias[j]);
    }
}

// ---------------- BatchNorm: stats then apply (blockDim == Ccols) ----------------
__global__ void bn_stats(const float* __restrict__ X, int R,
                         float* __restrict__ sum, float* __restrict__ sumsq)
{
    int t = threadIdx.x;
    int C = blockDim.x;
    float s = 0.f, s2 = 0.f;
    for (int r = blockIdx.x; r < R; r += gridDim.x) {
        float v = X[(size_t)r * C + t];
        s += v; s2 += v * v;
    }
    atomicAdd(&sum[t], s);
    atomicAdd(&sumsq[t], s2);
}

__global__ void bn_apply(float* __restrict__ X, int R,
                         const float* __restrict__ sum, const float* __restrict__ sumsq,
                         const float* __restrict__ gam, const float* __restrict__ bet,
                         const float* __restrict__ w, float* __restrict__ score)
{
    __shared__ float red[8];
    __shared__ float wred;
    int t = threadIdx.x;
    int C = blockDim.x;
    int nw = C >> 6;
    float invR = 1.f / (float)R;
    float mu = sum[t] * invR;
    float var = sumsq[t] * invR - mu * mu;
    float inv = 1.f / sqrtf(var + 1e-5f);
    float ga = gam[t] * inv;
    float be = bet[t] - mu * ga;
    float wt = 0.f, winv = 0.f;
    if (score) {
        wt = w[t];
        float p = wt * wt;
        for (int o = 32; o > 0; o >>= 1) p += __shfl_down(p, o, 64);
        if ((t & 63) == 0) red[t >> 6] = p;
        __syncthreads();
        if (t == 0) { float s = 0.f; for (int i = 0; i < nw; ++i) s += red[i]; wred = 1.f / sqrtf(s); }
        __syncthreads();
        winv = wred;
        __syncthreads();
    }
    for (int r = blockIdx.x; r < R; r += gridDim.x) {
        size_t idx = (size_t)r * C + t;
        float v = X[idx] * ga + be;
        X[idx] = v;
        if (score) {
            float p = v * wt;
            for (int o = 32; o > 0; o >>= 1) p += __shfl_down(p, o, 64);
            if ((t & 63) == 0) red[t >> 6] = p;
            __syncthreads();
            if (t == 0) { float s = 0.f; for (int i = 0; i < nw; ++i) s += red[i]; score[r] = s * winv; }
            __syncthreads();
        }
    }
}

// ---------------- TopK pool 0 (32 -> 23) ----------------
__global__ void topk0(const float* __restrict__ score,
                      int* __restrict__ newid, int* __restrict__ oldofnew)
{
    __shared__ float s[NAST];
    int g = blockIdx.x, t = threadIdx.x;
    if (t < NAST) s[t] = score[g * NAST + t];
    __syncthreads();
    if (t < NAST) {
        float v = s[t]; int rank = 0;
        for (int j = 0; j < NAST; ++j) rank += (s[j] > v) || (s[j] == v && j < t);
        bool keep = rank < K0;
        newid[g * NAST + t] = keep ? (g * K0 + rank) : -1;
        if (keep) oldofnew[g * K0 + rank] = g * NAST + t;
    }
}

__global__ void build_par1(const int* __restrict__ oldofnew, const int* __restrict__ newid,
                           const int* __restrict__ ast_src, int* __restrict__ par)
{
    int n = blockIdx.x * 256 + threadIdx.x;
    if (n >= N1) return;
    int g = n / K0;
    int oldg = oldofnew[n];
    int j = oldg - g * NAST;
    int p = -1;
    if (j > 0) p = newid[ast_src[g * (NAST - 1) + j - 1]];
    par[n] = p;
}

// ---------------- GAT1 attention (per pooled graph, in place) ----------------
__global__ __launch_bounds__(256) void gat1_att(
    float* __restrict__ h, const int* __restrict__ par,
    const float* __restrict__ asrc_w, const float* __restrict__ adst_w,
    const float* __restrict__ bias)
{
    __shared__ float hs[K0 * H_IN];
    __shared__ float as_[K0], ad_[K0], aS[K0], aP[K0];
    __shared__ int parl[K0];
    int g = blockIdx.x, tid = threadIdx.x;
    const float4* src4 = (const float4*)(h + (size_t)g * K0 * H_IN);
    float4* hs4 = (float4*)hs;
    for (int i = tid; i < K0 * H_IN / 4; i += 256) hs4[i] = src4[i];
    if (tid < K0) { int p = par[g * K0 + tid]; parl[tid] = (p >= 0) ? (p - g * K0) : -1; }
    __syncthreads();
    if (tid < K0 * 2) {
        int r = tid >> 1, sd = tid & 1;
        const float* w = sd ? adst_w : asrc_w;
        const float* row = hs + r * H_IN;
        float acc = 0.f;
        for (int c = 0; c < H_IN; ++c) acc += row[c] * w[c];
        if (sd) ad_[r] = acc; else as_[r] = acc;
    }
    __syncthreads();
    if (tid < K0) {
        int p = parl[tid];
        if (p < 0) { aS[tid] = 1.f; aP[tid] = 0.f; }
        else {
            float ls = as_[tid] + ad_[tid]; ls = ls > 0 ? ls : 0.2f * ls;
            float lp = as_[p] + ad_[tid]; lp = lp > 0 ? lp : 0.2f * lp;
            float m = fmaxf(ls, lp);
            float es = expf(ls - m), ep = expf(lp - m);
            float inv = 1.f / (es + ep);
            aS[tid] = es * inv; aP[tid] = ep * inv;
        }
    }
    __syncthreads();
    for (int i = tid; i < K0 * H_IN; i += 256) {
        int r = i >> 6, c = i & 63;
        int p = parl[r];
        float v = aS[r] * hs[r * H_IN + c];
        if (p >= 0) v += aP[r] * hs[p * H_IN + c];
        h[(size_t)g * K0 * H_IN + i] = tanhf(v + bias[c]);
    }
}

// ---------------- TopK pool 1 (23 -> 12) + global max pool + relu ----------------
__global__ void topk1_maxpool(const float* __restrict__ h, const float* __restrict__ score,
                              float* __restrict__ out)
{
    __shared__ float s[K0];
    __shared__ float gate[K0];
    __shared__ int keep[K0];
    int g = blockIdx.x, t = threadIdx.x;  // 64 threads
    if (t < K0) s[t] = score[g * K0 + t];
    __syncthreads();
    if (t < K0) {
        float v = s[t]; int rank = 0;
        for (int j = 0; j < K0; ++j) rank += (s[j] > v) || (s[j] == v && j < t);
        keep[t] = rank < K1;
        gate[t] = tanhf(v);
    }
    __syncthreads();
    float mx = -1e30f;
    const float* base = h + (size_t)g * K0 * H_IN;
    for (int j = 0; j < K0; ++j)
        if (keep[j]) mx = fmaxf(mx, base[j * H_IN + t] * gate[j]);
    out[g * H_IN + t] = fmaxf(mx, 0.f);
}

// ---------------- encoder MLP: [G,64] -> relu(@w1+b1) -> @w2+b2 -> [G,128] ----------------
__global__ __launch_bounds__(128) void enc_mlp(
    const float* __restrict__ in,
    const float* __restrict__ w1, const float* __restrict__ b1,
    const float* __restrict__ w2, const float* __restrict__ b2,
    float* __restrict__ out)
{
    __shared__ float row[64];
    __shared__ float t1[64];
    int g = blockIdx.x, t = threadIdx.x;
    if (t < 64) row[t] = in[g * 64 + t];
    __syncthreads();
    if (t < 64) {
        float acc = b1[t];
        for (int k = 0; k < 64; ++k) acc += row[k] * w1[k * 64 + t];
        t1[t] = fmaxf(acc, 0.f);
    }
    __syncthreads();
    float acc = b2[t];
    for (int k = 0; k < 64; ++k) acc += t1[k] * w2[k * 128 + t];
    out[(size_t)g * 128 + t] = acc;
}

// ---------------- RGAT qi/kj precompute (3 heads, 384 dims) ----------------
__global__ __launch_bounds__(256) void rgat_qk3(
    const float* __restrict__ h0, const float* __restrict__ h1,
    const float* __restrict__ q, const float* __restrict__ k,
    float* __restrict__ qi, float* __restrict__ kj)   // [2][NSTMT][3]
{
    int n = blockIdx.x, t = threadIdx.x;
    float p[12] = {};
    for (int d = t; d < HO3; d += 256) {
        float v0 = h0[(size_t)n * HO3 + d], v1 = h1[(size_t)n * HO3 + d];
        #pragma unroll
        for (int hh = 0; hh < 3; ++hh) {
            float qw = q[d * 3 + hh], kw = k[d * 3 + hh];
            p[hh]     += v0 * qw;  p[3 + hh] += v0 * kw;
            p[6 + hh] += v1 * qw;  p[9 + hh] += v1 * kw;
        }
    }
    __shared__ float red[4][12];
    #pragma unroll
    for (int i = 0; i < 12; ++i) {
        float x = p[i];
        for (int o = 32; o > 0; o >>= 1) x += __shfl_down(x, o, 64);
        if ((t & 63) == 0) red[t >> 6][i] = x;
    }
    __syncthreads();
    if (t < 12) {
        float s = red[0][t] + red[1][t] + red[2][t] + red[3][t];
        int rel = t / 6, rem = t % 6, isk = rem / 3, hh = rem % 3;
        float* dst = isk ? kj : qi;
        dst[((size_t)rel * NSTMT + n) * 3 + hh] = s;
    }
}

__global__ void edge_logits3(const int* __restrict__ src, const int* __restrict__ dst,
                             const int* __restrict__ et,
                             const float* __restrict__ qi, const float* __restrict__ kj,
                             float* __restrict__ logits)
{
    int e = blockIdx.x * 256 + threadIdx.x;
    if (e >= EST) return;
    int r = et[e], s = src[e], d = dst[e];
    #pragma unroll
    for (int hh = 0; hh < 3; ++hh) {
        float x = qi[((size_t)r * NSTMT + d) * 3 + hh] + kj[((size_t)r * NSTMT + s) * 3 + hh];
        logits[e * 3 + hh] = x > 0 ? x : 0.2f * x;
    }
}

// ---------------- CSR build ----------------
__global__ void count_deg(const int* __restrict__ dst, int* __restrict__ deg)
{
    int e = blockIdx.x * 256 + threadIdx.x;
    if (e < EST) atomicAdd(&deg[dst[e]], 1);
}

__global__ void scan_deg(const int* __restrict__ deg, int* __restrict__ offa)
{
    __shared__ int ts[1024];
    int t = threadIdx.x;
    int base = t * 8;
    int loc[8]; int s = 0;
    #pragma unroll
    for (int i = 0; i < 8; ++i) { loc[i] = s; s += deg[base + i]; }
    ts[t] = s;
    __syncthreads();
    for (int o = 1; o < 1024; o <<= 1) {
        int v = (t >= o) ? ts[t - o] : 0;
        __syncthreads();
        ts[t] += v;
        __syncthreads();
    }
    int prev = (t == 0) ? 0 : ts[t - 1];
    #pragma unroll
    for (int i = 0; i < 8; ++i) offa[base + i] = prev + loc[i];
    if (t == 1023) offa[8192] = ts[1023];
}

__global__ void scatter_csr(const int* __restrict__ dst, const int* __restrict__ offa,
                            int* __restrict__ cnt, int* __restrict__ csr)
{
    int e = blockIdx.x * 256 + threadIdx.x;
    if (e < EST) {
        int d = dst[e];
        int pos = offa[d] + atomicAdd(&cnt[d], 1);
        csr[pos] = e;
    }
}

// ---------------- RGAT0 aggregate (3 heads, 384 dims) + bias + tanh ----------------
__global__ __launch_bounds__(256) void rgat_agg3(
    const float* __restrict__ h0, const float* __restrict__ h1,
    const int* __restrict__ offa, const int* __restrict__ csr,
    const int* __restrict__ src, const int* __restrict__ et,
    const float* __restrict__ logits, const float* __restrict__ bias,
    float* __restrict__ out)
{
    int n = blockIdx.x, t = threadIdx.x;
    int o0 = offa[n], deg = offa[n + 1] - o0;
    __shared__ float m[3], sden[3];
    __shared__ float al[64][3];
    __shared__ int esrc[64], erel[64];
    if (t < 3) {
        float mm = -1e30f;
        for (int i = 0; i < deg; ++i) mm = fmaxf(mm, logits[csr[o0 + i] * 3 + t]);
        float ss = 0.f;
        for (int i = 0; i < deg; ++i) ss += expf(logits[csr[o0 + i] * 3 + t] - mm);
        m[t] = mm; sden[t] = fmaxf(ss, 1e-16f);
    }
    __syncthreads();
    float acc0 = 0.f, acc1 = 0.f;
    for (int c0 = 0; c0 < deg; c0 += 64) {
        int cn = min(64, deg - c0);
        if (t < cn) { int e = csr[o0 + c0 + t]; esrc[t] = src[e]; erel[t] = et[e]; }
        if (t < cn * 3) {
            int ee = t / 3, hh = t % 3;
            int e = csr[o0 + c0 + ee];
            al[ee][hh] = expf(logits[e * 3 + hh] - m[hh]) / sden[hh];
        }
        __syncthreads();
        for (int i = 0; i < cn; ++i) {
            const float* hb = (erel[i] ? h1 : h0) + (size_t)esrc[i] * HO3;
            acc0 += al[i][t >> 7] * hb[t];
            if (t < 128) acc1 += al[i][(t + 256) >> 7] * hb[t + 256];
        }
        __syncthreads();
    }
    out[(size_t)n * HO3 + t] = tanhf(acc0 + bias[t]);
    if (t < 128) out[(size_t)n * HO3 + t + 256] = tanhf(acc1 + bias[t + 256]);
}

// ---------------- RGAT1 qi/kj (1 head, 128 dims) ----------------
__global__ __launch_bounds__(128) void rgat_qk1(
    const float* __restrict__ h0, const float* __restrict__ h1,
    const float* __restrict__ q, const float* __restrict__ k,
    float* __restrict__ qi, float* __restrict__ kj)   // [2][NSTMT]
{
    int n = blockIdx.x, t = threadIdx.x;
    float v0 = h0[(size_t)n * 128 + t], v1 = h1[(size_t)n * 128 + t];
    float p0 = v0 * q[t], p1 = v0 * k[t], p2 = v1 * q[t], p3 = v1 * k[t];
    __shared__ float red[2][4];
    for (int o = 32; o > 0; o >>= 1) {
        p0 += __shfl_down(p0, o, 64); p1 += __shfl_down(p1, o, 64);
        p2 += __shfl_down(p2, o, 64); p3 += __shfl_down(p3, o, 64);
    }
    if ((t & 63) == 0) { int w = t >> 6; red[w][0] = p0; red[w][1] = p1; red[w][2] = p2; red[w][3] = p3; }
    __syncthreads();
    if (t < 4) {
        float s = red[0][t] + red[1][t];
        if (t == 0) qi[n] = s;
        else if (t == 1) kj[n] = s;
        else if (t == 2) qi[NSTMT + n] = s;
        else kj[NSTMT + n] = s;
    }
}

__global__ void edge_logits1(const int* __restrict__ src, const int* __restrict__ dst,
                             const int* __restrict__ et,
                             const float* __restrict__ qi, const float* __restrict__ kj,
                             float* __restrict__ logits)
{
    int e = blockIdx.x * 256 + threadIdx.x;
    if (e >= EST) return;
    int r = et[e], s = src[e], d = dst[e];
    float x = qi[(size_t)r * NSTMT + d] + kj[(size_t)r * NSTMT + s];
    logits[e] = x > 0 ? x : 0.2f * x;
}

// ---------------- RGAT1 aggregate (1 head, 128 dims) + bias + tanh ----------------
__global__ __launch_bounds__(128) void rgat_agg1(
    const float* __restrict__ h0, const float* __restrict__ h1,
    const int* __restrict__ offa, const int* __restrict__ csr,
    const int* __restrict__ src, const int* __restrict__ et,
    const float* __restrict__ logits, const float* __restrict__ bias,
    float* __restrict__ out)
{
    int n = blockIdx.x, t = threadIdx.x;
    int o0 = offa[n], deg = offa[n + 1] - o0;
    __shared__ float m1, s1;
    __shared__ float al[64];
    __shared__ int esrc[64], erel[64];
    if (t == 0) {
        float mm = -1e30f;
        for (int i = 0; i < deg; ++i) mm = fmaxf(mm, logits[csr[o0 + i]]);
        float ss = 0.f;
        for (int i = 0; i < deg; ++i) ss += expf(logits[csr[o0 + i]] - mm);
        m1 = mm; s1 = fmaxf(ss, 1e-16f);
    }
    __syncthreads();
    float acc = 0.f;
    for (int c0 = 0; c0 < deg; c0 += 64) {
        int cn = min(64, deg - c0);
        if (t < cn) {
            int e = csr[o0 + c0 + t];
            esrc[t] = src[e]; erel[t] = et[e];
            al[t] = expf(logits[e] - m1) / s1;
        }
        __syncthreads();
        for (int i = 0; i < cn; ++i)
            acc += al[i] * ((erel[i] ? h1 : h0)[(size_t)esrc[i] * 128 + t]);
        __syncthreads();
    }
    out[(size_t)n * 128 + t] = tanhf(acc + bias[t]);
}

// ---------------- classifier: gather sel + MLP + sigmoid ----------------
__global__ __launch_bounds__(128) void classifier(
    const float* __restrict__ x, const int* __restrict__ sel,
    const float* __restrict__ w1, const float* __restrict__ b1,
    const float* __restrict__ w2, const float* __restrict__ b2,
    float* __restrict__ out)
{
    __shared__ float row[128];
    __shared__ float t1[128];
    __shared__ float red[2];
    int b = blockIdx.x, t = threadIdx.x;
    int n = sel[b];
    row[t] = x[(size_t)n * 128 + t];
    __syncthreads();
    float acc = b1[t];
    for (int k = 0; k < 128; ++k) acc += row[k] * w1[k * 128 + t];
    t1[t] = fmaxf(acc, 0.f);
    __syncthreads();
    float p = t1[t] * w2[t];
    for (int o = 32; o > 0; o >>= 1) p += __shfl_down(p, o, 64);
    if ((t & 63) == 0) red[t >> 6] = p;
    __syncthreads();
    if (t == 0) {
        float z = red[0] + red[1] + b2[0];
        out[b] = 1.f / (1.f + expf(-z));
    }
}

// ---------------- workspace layout (bytes) ----------------
constexpr size_t OFF_HA     = 0;                                   // 262144*192*4 = 201326592
constexpr size_t OFF_SCORE0 = 201326592;                           // +1048576
constexpr size_t OFF_NEWID0 = OFF_SCORE0 + 1048576;                // +1048576
constexpr size_t OFF_OLDOF  = OFF_NEWID0 + 1048576;                // +753664
constexpr size_t OFF_PAR1   = OFF_OLDOF + 753664;                  // +753664
constexpr size_t OFF_HB     = OFF_PAR1 + 753664;                   // +48234496
constexpr size_t OFF_SCORE1 = OFF_HB + 48234496;                   // +753664
constexpr size_t OFF_GFEAT  = OFF_SCORE1 + 753664;                 // +2097152
constexpr size_t OFF_XENC   = OFF_GFEAT + 2097152;                 // +4194304
constexpr size_t OFF_BNSUM  = OFF_XENC + 4194304;                  // +1536
constexpr size_t OFF_BNSQ   = OFF_BNSUM + 1536;                    // +1536
constexpr size_t WS_NEEDED  = OFF_BNSQ + 1536;
// stage B aliases inside the (dead) hA region:
constexpr size_t OFF_H0R  = 0;                  // 12582912
constexpr size_t OFF_H1R  = 12582912;           // 12582912
constexpr size_t OFF_OUT0 = 25165824;           // 12582912
constexpr size_t OFF_G0   = 37748736;           // 4194304
constexpr size_t OFF_G1   = 41943040;           // 4194304
constexpr size_t OFF_OUT1 = 46137344;           // 4194304
constexpr size_t OFF_QI3  = 50331648;           // 196608
constexpr size_t OFF_KJ3  = 50528256;           // 196608
constexpr size_t OFF_LG3  = 50724864;           // 393216
constexpr size_t OFF_QI1  = 51118080;           // 65536
constexpr size_t OFF_KJ1  = 51183616;           // 65536
constexpr size_t OFF_LG1  = 51249152;           // 131072
constexpr size_t OFF_DEG  = 51380224;           // 32768
constexpr size_t OFF_OFFA = 51412992;           // 33024
constexpr size_t OFF_CNT  = 51446016;           // 32768
constexpr size_t OFF_CSR  = 51478784;           // 131072

extern "C" void kernel_launch(void* const* d_in, const int* in_sizes, int n_in,
                              void* d_out, int out_size, void* d_ws, size_t ws_size,
                              hipStream_t stream)
{
    if (n_in < 41 || ws_size < WS_NEEDED) return;

    const float* ast_x    = (const float*)d_in[0];
    const int*   ast_src  = (const int*)d_in[1];
    const int*   stmt_src = (const int*)d_in[3];
    const int*   stmt_dst = (const int*)d_in[4];
    const int*   stmt_et  = (const int*)d_in[5];
    const int*   sel      = (const int*)d_in[6];
    const float* gat0_W    = (const float*)d_in[7];
    const float* gat0_asrc = (const float*)d_in[8];
    const float* gat0_adst = (const float*)d_in[9];
    const float* gat0_b    = (const float*)d_in[10];
    const float* bn0_g     = (const float*)d_in[11];
    const float* bn0_b     = (const float*)d_in[12];
    const float* pool0_w   = (const float*)d_in[13];
    const float* gat1_W    = (const float*)d_in[14];
    const float* gat1_asrc = (const float*)d_in[15];
    const float* gat1_adst = (const float*)d_in[16];
    const float* gat1_b    = (const float*)d_in[17];
    const float* bn1_g     = (const float*)d_in[18];
    const float* bn1_b     = (const float*)d_in[19];
    const float* pool1_w   = (const float*)d_in[20];
    const float* enc_w1    = (const float*)d_in[21];
    const float* enc_b1    = (const float*)d_in[22];
    const float* enc_w2    = (const float*)d_in[23];
    const float* enc_b2    = (const float*)d_in[24];
    const float* rgat0_W   = (const float*)d_in[25];
    const float* rgat0_q   = (const float*)d_in[26];
    const float* rgat0_k   = (const float*)d_in[27];
    const float* rgat0_b   = (const float*)d_in[28];
    const float* bnc0_g    = (const float*)d_in[29];
    const float* bnc0_b    = (const float*)d_in[30];
    const float* rgat1_W   = (const float*)d_in[31];
    const float* rgat1_q   = (const float*)d_in[32];
    const float* rgat1_k   = (const float*)d_in[33];
    const float* rgat1_b   = (const float*)d_in[34];
    const float* bnc1_g    = (const float*)d_in[35];
    const float* bnc1_b    = (const float*)d_in[36];
    const float* clf_w1    = (const float*)d_in[37];
    const float* clf_b1    = (const float*)d_in[38];
    const float* clf_w2    = (const float*)d_in[39];
    const float* clf_b2    = (const float*)d_in[40];

    char* ws = (char*)d_ws;
    float* hA     = (float*)(ws + OFF_HA);
    float* score0 = (float*)(ws + OFF_SCORE0);
    int*   newid0 = (int*)(ws + OFF_NEWID0);
    int*   oldof  = (int*)(ws + OFF_OLDOF);
    int*   par1   = (int*)(ws + OFF_PAR1);
    float* hB     = (float*)(ws + OFF_HB);
    float* score1 = (float*)(ws + OFF_SCORE1);
    float* gfeat  = (float*)(ws + OFF_GFEAT);
    float* xenc   = (float*)(ws + OFF_XENC);
    float* bnsum  = (float*)(ws + OFF_BNSUM);
    float* bnsq   = (float*)(ws + OFF_BNSQ);
    // stage B aliases (hA dead after the gather GEMM)
    float* h0r  = (float*)(ws + OFF_H0R);
    float* h1r  = (float*)(ws + OFF_H1R);
    float* out0 = (float*)(ws + OFF_OUT0);
    float* g0   = (float*)(ws + OFF_G0);
    float* g1   = (float*)(ws + OFF_G1);
    float* out1 = (float*)(ws + OFF_OUT1);
    float* qi3  = (float*)(ws + OFF_QI3);
    float* kj3  = (float*)(ws + OFF_KJ3);
    float* lg3  = (float*)(ws + OFF_LG3);
    float* qi1  = (float*)(ws + OFF_QI1);
    float* kj1  = (float*)(ws + OFF_KJ1);
    float* lg1  = (float*)(ws + OFF_LG1);
    int*   deg  = (int*)(ws + OFF_DEG);
    int*   offa = (int*)(ws + OFF_OFFA);
    int*   cnt  = (int*)(ws + OFF_CNT);
    int*   csr  = (int*)(ws + OFF_CSR);

    // ---- Stage A: statement encoder ----
    gemm_nn<false><<<dim3(N0 / 64, C0 / 64), 256, 0, stream>>>(ast_x, gat0_W, hA, N0, C0, D_EMB, nullptr, nullptr);
    gat0_att<<<G, 256, 0, stream>>>(hA, ast_src, gat0_asrc, gat0_adst, gat0_b);
    hipMemsetAsync(bnsum, 0, 3072, stream);
    bn_stats<<<2048, C0, 0, stream>>>(hA, N0, bnsum, bnsq);
    bn_apply<<<2048, C0, 0, stream>>>(hA, N0, bnsum, bnsq, bn0_g, bn0_b, pool0_w, score0);
    topk0<<<G, 64, 0, stream>>>(score0, newid0, oldof);
    build_par1<<<(N1 + 255) / 256, 256, 0, stream>>>(oldof, newid0, ast_src, par1);
    gemm_nn<true><<<dim3(N1 / 64, 1), 256, 0, stream>>>(hA, gat1_W, hB, N1, H_IN, C0, oldof, score0);
    gat1_att<<<G, 256, 0, stream>>>(hB, par1, gat1_asrc, gat1_adst, gat1_b);
    hipMemsetAsync(bnsum, 0, 3072, stream);
    bn_stats<<<2048, H_IN, 0, stream>>>(hB, N1, bnsum, bnsq);
    bn_apply<<<2048, H_IN, 0, stream>>>(hB, N1, bnsum, bnsq, bn1_g, bn1_b, pool1_w, score1);
    topk1_maxpool<<<G, 64, 0, stream>>>(hB, score1, gfeat);
    enc_mlp<<<G, 128, 0, stream>>>(gfeat, enc_w1, enc_b1, enc_w2, enc_b2, xenc);

    // ---- Stage B: statement classifier ----
    gemm_nn<false><<<dim3(NSTMT / 64, HO3 / 64), 256, 0, stream>>>(xenc, rgat0_W, h0r, NSTMT, HO3, ENC, nullptr, nullptr);
    gemm_nn<false><<<dim3(NSTMT / 64, HO3 / 64), 256, 0, stream>>>(xenc, rgat0_W + (size_t)ENC * HO3, h1r, NSTMT, HO3, ENC, nullptr, nullptr);
    rgat_qk3<<<NSTMT, 256, 0, stream>>>(h0r, h1r, rgat0_q, rgat0_k, qi3, kj3);
    edge_logits3<<<EST / 256, 256, 0, stream>>>(stmt_src, stmt_dst, stmt_et, qi3, kj3, lg3);
    hipMemsetAsync(deg, 0, 32768, stream);
    hipMemsetAsync(cnt, 0, 32768, stream);
    count_deg<<<EST / 256, 256, 0, stream>>>(stmt_dst, deg);
    scan_deg<<<1, 1024, 0, stream>>>(deg, offa);
    scatter_csr<<<EST / 256, 256, 0, stream>>>(stmt_dst, offa, cnt, csr);
    rgat_agg3<<<NSTMT, 256, 0, stream>>>(h0r, h1r, offa, csr, stmt_src, stmt_et, lg3, rgat0_b, out0);
    hipMemsetAsync(bnsum, 0, 3072, stream);
    bn_stats<<<256, HO3, 0, stream>>>(out0, NSTMT, bnsum, bnsq);
    bn_apply<<<256, HO3, 0, stream>>>(out0, NSTMT, bnsum, bnsq, bnc0_g, bnc0_b, nullptr, nullptr);
    gemm_nn<false><<<dim3(NSTMT / 64, HOUT / 64), 256, 0, stream>>>(out0, rgat1_W, g0, NSTMT, HOUT, HO3, nullptr, nullptr);
    gemm_nn<false><<<dim3(NSTMT / 64, HOUT / 64), 256, 0, stream>>>(out0, rgat1_W + (size_t)HO3 * HOUT, g1, NSTMT, HOUT, HO3, nullptr, nullptr);
    rgat_qk1<<<NSTMT, 128, 0, stream>>>(g0, g1, rgat1_q, rgat1_k, qi1, kj1);
    edge_logits1<<<EST / 256, 256, 0, stream>>>(stmt_src, stmt_dst, stmt_et, qi1, kj1, lg1);
    rgat_agg1<<<NSTMT, 128, 0, stream>>>(g0, g1, offa, csr, stmt_src, stmt_et, lg1, rgat1_b, out1);
    hipMemsetAsync(bnsum, 0, 3072, stream);
    bn_stats<<<256, HOUT, 0, stream>>>(out1, NSTMT, bnsum, bnsq);
    bn_apply<<<256, HOUT, 0, stream>>>(out1, NSTMT, bnsum, bnsq, bnc1_g, bnc1_b, nullptr, nullptr);
    classifier<<<NSEL, 128, 0, stream>>>(out1, sel, clf_w1, clf_b1, clf_w2, clf_b2, (float*)d_out);
}

// Round 2
// 984.614 us; speedup vs baseline: 1.2818x; 1.2818x over previous
//
#include <hip/hip_runtime.h>
#include <cstddef>
#include <cstdint>

// ---------------- problem constants ----------------
constexpr int G      = 8192;
constexpr int NAST   = 32;
constexpr int N0     = G * NAST;    // 262144
constexpr int D_EMB  = 128;
constexpr int C0     = 192;         // 3 * H_IN
constexpr int H_IN   = 64;
constexpr int K0     = 23;          // ceil(0.7*32)
constexpr int N1     = G * K0;      // 188416
constexpr int K1     = 12;          // ceil(0.5*23)
constexpr int ENC    = 128;
constexpr int NSTMT  = 8192;
constexpr int EST    = 32768;
constexpr int HO3    = 384;
constexpr int HOUT   = 128;
constexpr int NSEL   = 4096;

// =====================================================================
// Fused GAT0: per-block = 2 AST graphs (64 rows), full 192 cols, K=128.
// GEMM (fp32) -> GAT attention (parent/self softmax) -> +bias -> tanh
// -> write hA + per-block BN column partials.
// =====================================================================
__global__ __launch_bounds__(256) void fused_gat0(
    const float* __restrict__ X, const float* __restrict__ W,
    const int* __restrict__ ast_src,
    const float* __restrict__ asrc_w, const float* __restrict__ adst_w,
    const float* __restrict__ bias,
    float* __restrict__ out, float* __restrict__ psum, float* __restrict__ psq)
{
    __shared__ char smem[52736];
    int tid = threadIdx.x;
    int b = blockIdx.x;
    int row0 = b * 64;

    // phase-1 views
    float* As = (float*)smem;          // [32][65]  (k-major, padded)
    float* Bs = As + 32 * 65;          // [32][200] (k-major, padded)

    int ra = tid >> 3;                 // 0..31 : node within each graph
    int c0 = (tid & 7) * 24;           // col group
    int lr = tid >> 2;                 // A-load row 0..63
    int lk = (tid & 3) * 8;            // A-load k offset
    int bkk = tid >> 3;                // B-load k row 0..31
    int bc0 = (tid & 7) * 24;          // B-load col group

    float acc0[24] = {};               // graph 0, node ra
    float acc1[24] = {};               // graph 1, node ra

    for (int kt = 0; kt < 128; kt += 32) {
        const float* ap = X + (size_t)(row0 + lr) * 128 + kt + lk;
        float4 a0 = *(const float4*)ap;
        float4 a1 = *(const float4*)(ap + 4);
        As[(lk + 0) * 65 + lr] = a0.x; As[(lk + 1) * 65 + lr] = a0.y;
        As[(lk + 2) * 65 + lr] = a0.z; As[(lk + 3) * 65 + lr] = a0.w;
        As[(lk + 4) * 65 + lr] = a1.x; As[(lk + 5) * 65 + lr] = a1.y;
        As[(lk + 6) * 65 + lr] = a1.z; As[(lk + 7) * 65 + lr] = a1.w;
        const float* bp = W + (size_t)(kt + bkk) * 192 + bc0;
        #pragma unroll
        for (int u = 0; u < 6; ++u)
            *(float4*)&Bs[bkk * 200 + bc0 + u * 4] = *(const float4*)(bp + u * 4);
        __syncthreads();
        #pragma unroll
        for (int kk = 0; kk < 32; ++kk) {
            float a0v = As[kk * 65 + ra];
            float a1v = As[kk * 65 + 32 + ra];
            const float* bb = &Bs[kk * 200 + c0];
            #pragma unroll
            for (int u = 0; u < 6; ++u) {
                float4 b4 = *(const float4*)(bb + u * 4);
                acc0[u * 4 + 0] += a0v * b4.x; acc1[u * 4 + 0] += a1v * b4.x;
                acc0[u * 4 + 1] += a0v * b4.y; acc1[u * 4 + 1] += a1v * b4.y;
                acc0[u * 4 + 2] += a0v * b4.z; acc1[u * 4 + 2] += a1v * b4.z;
                acc0[u * 4 + 3] += a0v * b4.w; acc1[u * 4 + 3] += a1v * b4.w;
            }
        }
        __syncthreads();
    }

    // phase-2 views (overwrite As/Bs)
    float* Cs  = (float*)smem;         // [64][193]
    float* as_ = Cs + 64 * 193;        // [64][3]
    float* ad_ = as_ + 192;
    float* aS  = ad_ + 192;
    float* aP  = aS + 192;
    int*  parl = (int*)(aP + 192);     // [64]

    #pragma unroll
    for (int u = 0; u < 24; ++u) {
        Cs[ra * 193 + c0 + u]        = acc0[u];
        Cs[(ra + 32) * 193 + c0 + u] = acc1[u];
    }
    if (tid < 62) {
        int q = tid / 31, j = tid % 31 + 1;
        int g = 2 * b + q;
        parl[q * 32 + j] = ast_src[(size_t)g * 31 + j - 1] - g * 32 + q * 32;
    }
    if (tid < 2) parl[tid * 32] = -1;
    __syncthreads();

    for (int task = tid; task < 384; task += 256) {
        int r = task / 6, q6 = task % 6, hh = q6 >> 1, sd = q6 & 1;
        const float* w = (sd ? adst_w : asrc_w) + hh * 64;
        const float* crow = &Cs[r * 193 + hh * 64];
        float s = 0.f;
        for (int c = 0; c < 64; ++c) s += crow[c] * w[c];
        (sd ? ad_ : as_)[r * 3 + hh] = s;
    }
    __syncthreads();
    if (tid < 192) {
        int r = tid / 3, hh = tid % 3, p = parl[r];
        if (p < 0) { aS[r * 3 + hh] = 1.f; aP[r * 3 + hh] = 0.f; }
        else {
            float ls = as_[r * 3 + hh] + ad_[r * 3 + hh]; ls = ls > 0 ? ls : 0.2f * ls;
            float lp = as_[p * 3 + hh] + ad_[r * 3 + hh]; lp = lp > 0 ? lp : 0.2f * lp;
            float m = fmaxf(ls, lp);
            float es = __expf(ls - m) , ep = __expf(lp - m);
            // use precise expf to match reference closely
            es = expf(ls - m); ep = expf(lp - m);
            float inv = 1.f / (es + ep);
            aS[r * 3 + hh] = es * inv; aP[r * 3 + hh] = ep * inv;
        }
    }
    __syncthreads();
    if (tid < 192) {
        int j = tid, hh = j >> 6;
        float bj = bias[j];
        float s = 0.f, s2 = 0.f;
        for (int r = 0; r < 64; ++r) {
            int p = parl[r];
            float v = aS[r * 3 + hh] * Cs[r * 193 + j];
            if (p >= 0) v += aP[r * 3 + hh] * Cs[p * 193 + j];
            v = tanhf(v + bj);
            out[(size_t)(row0 + r) * 192 + j] = v;
            s += v; s2 += v * v;
        }
        psum[(size_t)j * 4096 + b] = s;
        psq [(size_t)j * 4096 + b] = s2;
    }
}

// =====================================================================
// BN finalize: per column j, reduce per-block partials -> ga/be and
// score-folded gw = ga*w, bw = be*w.
// =====================================================================
__global__ __launch_bounds__(256) void bn_finalize(
    const float* __restrict__ psum, const float* __restrict__ psq, int nb, float R,
    const float* __restrict__ gamma, const float* __restrict__ beta,
    const float* __restrict__ w,
    float* __restrict__ ga, float* __restrict__ be,
    float* __restrict__ gw, float* __restrict__ bw)
{
    int j = blockIdx.x, t = threadIdx.x;
    const float* ps = psum + (size_t)j * nb;
    const float* pq = psq + (size_t)j * nb;
    float s = 0.f, s2 = 0.f;
    for (int i = t; i < nb; i += 256) { s += ps[i]; s2 += pq[i]; }
    __shared__ float r1[4], r2[4];
    for (int o = 32; o > 0; o >>= 1) { s += __shfl_down(s, o, 64); s2 += __shfl_down(s2, o, 64); }
    if ((t & 63) == 0) { r1[t >> 6] = s; r2[t >> 6] = s2; }
    __syncthreads();
    if (t == 0) {
        float S = r1[0] + r1[1] + r1[2] + r1[3];
        float S2 = r2[0] + r2[1] + r2[2] + r2[3];
        float mu = S / R, var = S2 / R - mu * mu;
        float inv = 1.f / sqrtf(var + 1e-5f);
        float gaj = gamma[j] * inv, bej = beta[j] - mu * gaj;
        ga[j] = gaj; be[j] = bej; gw[j] = gaj * w[j]; bw[j] = bej * w[j];
    }
}

// =====================================================================
// Score + TopK(32->23) + parent remap. Reads raw hA once.
// =====================================================================
__global__ __launch_bounds__(256) void score_topk0(
    const float* __restrict__ hA, const int* __restrict__ ast_src,
    const float* __restrict__ gw, const float* __restrict__ bw,
    const float* __restrict__ w,
    int* __restrict__ oldrow, float* __restrict__ gate23, int* __restrict__ parloc)
{
    __shared__ float swv[192];
    __shared__ float sc[32];
    __shared__ int nid[32];
    __shared__ float wparts[4], bparts[4];
    int g = blockIdx.x, t = threadIdx.x;
    if (t < 192) swv[t] = gw[t];
    float ws = (t < 192) ? w[t] * w[t] : 0.f;
    float bs = (t < 192) ? bw[t] : 0.f;
    for (int o = 32; o > 0; o >>= 1) { ws += __shfl_down(ws, o, 64); bs += __shfl_down(bs, o, 64); }
    if ((t & 63) == 0) { wparts[t >> 6] = ws; bparts[t >> 6] = bs; }
    __syncthreads();
    float invn = rsqrtf(wparts[0] + wparts[1] + wparts[2] + wparts[3]);
    invn = 1.f / sqrtf(1.f / (invn * invn));  // keep precise: recompute below
    {
        float tot = wparts[0] + wparts[1] + wparts[2] + wparts[3];
        invn = 1.f / sqrtf(tot);
    }
    float sb = bparts[0] + bparts[1] + bparts[2] + bparts[3];

    int r = t >> 3, j0 = (t & 7) * 24;
    const float* row = hA + ((size_t)g * 32 + r) * 192 + j0;
    const float4* row4 = (const float4*)row;
    const float4* sw4 = (const float4*)(swv + j0);
    float s = 0.f;
    #pragma unroll
    for (int u = 0; u < 6; ++u) {
        float4 a = row4[u], bv = sw4[u];
        s += a.x * bv.x + a.y * bv.y + a.z * bv.z + a.w * bv.w;
    }
    for (int o = 4; o > 0; o >>= 1) s += __shfl_down(s, o, 8);
    if ((t & 7) == 0) sc[r] = (s + sb) * invn;
    __syncthreads();
    if (t < 32) {
        float v = sc[t]; int rank = 0;
        for (int j = 0; j < 32; ++j) rank += (sc[j] > v) || (sc[j] == v && j < t);
        nid[t] = (rank < 23) ? rank : -1;
    }
    __syncthreads();
    if (t < 32 && nid[t] >= 0) {
        int rank = nid[t];
        oldrow[g * 23 + rank] = g * 32 + t;
        gate23[g * 23 + rank] = tanhf(sc[t]);
        int pl = -1;
        if (t > 0) {
            int p = ast_src[(size_t)g * 31 + t - 1] - g * 32;
            pl = nid[p];
        }
        parloc[g * 23 + rank] = pl;
    }
}

// =====================================================================
// Gather-GEMM: hB[N1,64] = relu((hA[old]*ga+be)*gate) @ gat1_W[192,64]
// =====================================================================
__global__ __launch_bounds__(256) void gemm_gather(
    const float* __restrict__ A, const float* __restrict__ B, float* __restrict__ C,
    const int* __restrict__ rowmap, const float* __restrict__ gate,
    const float* __restrict__ ga, const float* __restrict__ be)
{
    __shared__ float As[16 * 68];
    __shared__ float Bs[16 * 68];
    __shared__ float gas[192], bes[192];
    int tid = threadIdx.x, bm = blockIdx.x;
    if (tid < 192) { gas[tid] = ga[tid]; bes[tid] = be[tid]; }
    int arow = tid >> 2, aks = (tid & 3) * 4;
    int brow = tid >> 4, bns = (tid & 15) * 4;
    int tm = tid >> 4, tn = tid & 15;
    float acc[4][4] = {};
    int grow = bm * 64 + arow;
    int old = rowmap[grow];
    float gt = gate[grow];
    const float* ap = A + (size_t)old * 192;
    __syncthreads();
    for (int kt = 0; kt < 192; kt += 16) {
        float4 av = *(const float4*)(ap + kt + aks);
        int kb = kt + aks;
        av.x = fmaxf((av.x * gas[kb + 0] + bes[kb + 0]) * gt, 0.f);
        av.y = fmaxf((av.y * gas[kb + 1] + bes[kb + 1]) * gt, 0.f);
        av.z = fmaxf((av.z * gas[kb + 2] + bes[kb + 2]) * gt, 0.f);
        av.w = fmaxf((av.w * gas[kb + 3] + bes[kb + 3]) * gt, 0.f);
        As[(aks + 0) * 68 + arow] = av.x;
        As[(aks + 1) * 68 + arow] = av.y;
        As[(aks + 2) * 68 + arow] = av.z;
        As[(aks + 3) * 68 + arow] = av.w;
        *(float4*)&Bs[brow * 68 + bns] = *(const float4*)(B + (size_t)(kt + brow) * 64 + bns);
        __syncthreads();
        #pragma unroll
        for (int kk = 0; kk < 16; ++kk) {
            float4 a4 = *(const float4*)&As[kk * 68 + (tm << 2)];
            float4 b4 = *(const float4*)&Bs[kk * 68 + (tn << 2)];
            float a_[4] = {a4.x, a4.y, a4.z, a4.w};
            float b_[4] = {b4.x, b4.y, b4.z, b4.w};
            #pragma unroll
            for (int i = 0; i < 4; ++i)
                #pragma unroll
                for (int j = 0; j < 4; ++j)
                    acc[i][j] += a_[i] * b_[j];
        }
        __syncthreads();
    }
    #pragma unroll
    for (int i = 0; i < 4; ++i) {
        int rr = bm * 64 + (tm << 2) + i;
        float4 o = {acc[i][0], acc[i][1], acc[i][2], acc[i][3]};
        *(float4*)(C + (size_t)rr * 64 + (tn << 2)) = o;
    }
}

// =====================================================================
// GAT1 attention (in place on hB) + tanh + BN1 partials. 64 threads.
// =====================================================================
__global__ __launch_bounds__(64) void gat1_att_bn(
    float* __restrict__ h, const int* __restrict__ parloc,
    const float* __restrict__ aw_s, const float* __restrict__ aw_d,
    const float* __restrict__ bias,
    float* __restrict__ psum, float* __restrict__ psq)
{
    __shared__ float hs[23 * 65];
    __shared__ float as_[23], ad_[23], aS[23], aP[23];
    __shared__ int parl[23];
    int g = blockIdx.x, t = threadIdx.x;
    float* base = h + (size_t)g * 23 * 64;
    for (int r = 0; r < 23; ++r) hs[r * 65 + t] = base[r * 64 + t];
    if (t < 23) parl[t] = parloc[g * 23 + t];
    __syncthreads();
    if (t < 46) {
        int r = t >> 1, sd = t & 1;
        const float* w = sd ? aw_d : aw_s;
        const float* row = &hs[r * 65];
        float s = 0.f;
        for (int c = 0; c < 64; ++c) s += row[c] * w[c];
        (sd ? ad_ : as_)[r] = s;
    }
    __syncthreads();
    if (t < 23) {
        int p = parl[t];
        if (p < 0) { aS[t] = 1.f; aP[t] = 0.f; }
        else {
            float ls = as_[t] + ad_[t]; ls = ls > 0 ? ls : 0.2f * ls;
            float lp = as_[p] + ad_[t]; lp = lp > 0 ? lp : 0.2f * lp;
            float m = fmaxf(ls, lp);
            float es = expf(ls - m), ep = expf(lp - m);
            float inv = 1.f / (es + ep);
            aS[t] = es * inv; aP[t] = ep * inv;
        }
    }
    __syncthreads();
    float bj = bias[t], s = 0.f, s2 = 0.f;
    for (int r = 0; r < 23; ++r) {
        int p = parl[r];
        float v = aS[r] * hs[r * 65 + t];
        if (p >= 0) v += aP[r] * hs[p * 65 + t];
        v = tanhf(v + bj);
        base[r * 64 + t] = v;
        s += v; s2 += v * v;
    }
    psum[(size_t)t * 8192 + g] = s;
    psq [(size_t)t * 8192 + g] = s2;
}

// =====================================================================
// Score1 + TopK(23->12) + gated-BN maxpool + relu + encoder MLP -> xenc
// =====================================================================
__global__ __launch_bounds__(128) void pool1_mlp(
    const float* __restrict__ h,
    const float* __restrict__ gw, const float* __restrict__ bw,
    const float* __restrict__ w,
    const float* __restrict__ ga, const float* __restrict__ be,
    const float* __restrict__ w1, const float* __restrict__ b1,
    const float* __restrict__ w2, const float* __restrict__ b2,
    float* __restrict__ xenc)
{
    __shared__ float hs[23 * 65];
    __shared__ float sc[23];
    __shared__ int keep[23];
    __shared__ float feat[64], t1[64];
    __shared__ float consts[2];
    int g = blockIdx.x, t = threadIdx.x;
    const float* base = h + (size_t)g * 23 * 64;
    {
        int c = t & 63;
        for (int r = t >> 6; r < 23; r += 2) hs[r * 65 + c] = base[r * 64 + c];
    }
    if (t < 64) {
        float ws = w[t] * w[t], bs = bw[t];
        for (int o = 32; o > 0; o >>= 1) { ws += __shfl_down(ws, o, 64); bs += __shfl_down(bs, o, 64); }
        if (t == 0) { consts[0] = 1.f / sqrtf(ws); consts[1] = bs; }
    }
    __syncthreads();
    if (t < 23) {
        const float* row = &hs[t * 65];
        float s = 0.f;
        for (int c = 0; c < 64; ++c) s += row[c] * gw[c];
        sc[t] = (s + consts[1]) * consts[0];
    }
    __syncthreads();
    if (t < 23) {
        float v = sc[t]; int rank = 0;
        for (int j = 0; j < 23; ++j) rank += (sc[j] > v) || (sc[j] == v && j < t);
        keep[t] = rank < 12;
    }
    __syncthreads();
    if (t < 23) sc[t] = tanhf(sc[t]);
    __syncthreads();
    if (t < 64) {
        float m = -1e30f, gac = ga[t], bec = be[t];
        for (int r = 0; r < 23; ++r)
            if (keep[r]) m = fmaxf(m, (hs[r * 65 + t] * gac + bec) * sc[r]);
        feat[t] = fmaxf(m, 0.f);
    }
    __syncthreads();
    if (t < 64) {
        float acc = b1[t];
        for (int c = 0; c < 64; ++c) acc += feat[c] * w1[c * 64 + t];
        t1[t] = fmaxf(acc, 0.f);
    }
    __syncthreads();
    float acc = b2[t];
    for (int j = 0; j < 64; ++j) acc += t1[j] * w2[j * 128 + t];
    xenc[(size_t)g * 128 + t] = acc;
}

// =====================================================================
// Generic tiled GEMM (stage B): C[M,N] = A[M,K] @ B[K,N]
// =====================================================================
__global__ __launch_bounds__(256) void gemm_nn(
    const float* __restrict__ A, const float* __restrict__ B, float* __restrict__ C,
    int M, int N, int K)
{
    __shared__ float As[16 * 68];
    __shared__ float Bs[16 * 68];
    int tid = threadIdx.x;
    int bm = blockIdx.x, bn = blockIdx.y;
    int arow = tid >> 2, aks = (tid & 3) * 4;
    int brow = tid >> 4, bns = (tid & 15) * 4;
    int tm = tid >> 4, tn = tid & 15;
    float acc[4][4] = {};
    const float* ap = A + (size_t)(bm * 64 + arow) * K;
    for (int kt = 0; kt < K; kt += 16) {
        float4 av = *(const float4*)(ap + kt + aks);
        As[(aks + 0) * 68 + arow] = av.x;
        As[(aks + 1) * 68 + arow] = av.y;
        As[(aks + 2) * 68 + arow] = av.z;
        As[(aks + 3) * 68 + arow] = av.w;
        *(float4*)&Bs[brow * 68 + bns] = *(const float4*)(B + (size_t)(kt + brow) * N + bn * 64 + bns);
        __syncthreads();
        #pragma unroll
        for (int kk = 0; kk < 16; ++kk) {
            float4 a4 = *(const float4*)&As[kk * 68 + (tm << 2)];
            float4 b4 = *(const float4*)&Bs[kk * 68 + (tn << 2)];
            float a_[4] = {a4.x, a4.y, a4.z, a4.w};
            float b_[4] = {b4.x, b4.y, b4.z, b4.w};
            #pragma unroll
            for (int i = 0; i < 4; ++i)
                #pragma unroll
                for (int j = 0; j < 4; ++j)
                    acc[i][j] += a_[i] * b_[j];
        }
        __syncthreads();
    }
    #pragma unroll
    for (int i = 0; i < 4; ++i) {
        int r = bm * 64 + (tm << 2) + i;
        float4 o = {acc[i][0], acc[i][1], acc[i][2], acc[i][3]};
        *(float4*)(C + (size_t)r * N + bn * 64 + (tn << 2)) = o;
    }
}

// ---------------- BatchNorm (stage B) ----------------
__global__ void bn_stats(const float* __restrict__ X, int R,
                         float* __restrict__ sum, float* __restrict__ sumsq)
{
    int t = threadIdx.x;
    int C = blockDim.x;
    float s = 0.f, s2 = 0.f;
    for (int r = blockIdx.x; r < R; r += gridDim.x) {
        float v = X[(size_t)r * C + t];
        s += v; s2 += v * v;
    }
    atomicAdd(&sum[t], s);
    atomicAdd(&sumsq[t], s2);
}

__global__ void bn_apply(float* __restrict__ X, int R,
                         const float* __restrict__ sum, const float* __restrict__ sumsq,
                         const float* __restrict__ gam, const float* __restrict__ bet)
{
    int t = threadIdx.x;
    int C = blockDim.x;
    float invR = 1.f / (float)R;
    float mu = sum[t] * invR;
    float var = sumsq[t] * invR - mu * mu;
    float inv = 1.f / sqrtf(var + 1e-5f);
    float ga = gam[t] * inv;
    float be = bet[t] - mu * ga;
    for (int r = blockIdx.x; r < R; r += gridDim.x) {
        size_t idx = (size_t)r * C + t;
        X[idx] = X[idx] * ga + be;
    }
}

// ---------------- RGAT qi/kj precompute (3 heads, 384 dims) ----------------
__global__ __launch_bounds__(256) void rgat_qk3(
    const float* __restrict__ h0, const float* __restrict__ h1,
    const float* __restrict__ q, const float* __restrict__ k,
    float* __restrict__ qi, float* __restrict__ kj)
{
    int n = blockIdx.x, t = threadIdx.x;
    float p[12] = {};
    for (int d = t; d < HO3; d += 256) {
        float v0 = h0[(size_t)n * HO3 + d], v1 = h1[(size_t)n * HO3 + d];
        #pragma unroll
        for (int hh = 0; hh < 3; ++hh) {
            float qw = q[d * 3 + hh], kw = k[d * 3 + hh];
            p[hh]     += v0 * qw;  p[3 + hh] += v0 * kw;
            p[6 + hh] += v1 * qw;  p[9 + hh] += v1 * kw;
        }
    }
    __shared__ float red[4][12];
    #pragma unroll
    for (int i = 0; i < 12; ++i) {
        float x = p[i];
        for (int o = 32; o > 0; o >>= 1) x += __shfl_down(x, o, 64);
        if ((t & 63) == 0) red[t >> 6][i] = x;
    }
    __syncthreads();
    if (t < 12) {
        float s = red[0][t] + red[1][t] + red[2][t] + red[3][t];
        int rel = t / 6, rem = t % 6, isk = rem / 3, hh = rem % 3;
        float* dst = isk ? kj : qi;
        dst[((size_t)rel * NSTMT + n) * 3 + hh] = s;
    }
}

__global__ void edge_logits3(const int* __restrict__ src, const int* __restrict__ dst,
                             const int* __restrict__ et,
                             const float* __restrict__ qi, const float* __restrict__ kj,
                             float* __restrict__ logits)
{
    int e = blockIdx.x * 256 + threadIdx.x;
    if (e >= EST) return;
    int r = et[e], s = src[e], d = dst[e];
    #pragma unroll
    for (int hh = 0; hh < 3; ++hh) {
        float x = qi[((size_t)r * NSTMT + d) * 3 + hh] + kj[((size_t)r * NSTMT + s) * 3 + hh];
        logits[e * 3 + hh] = x > 0 ? x : 0.2f * x;
    }
}

// ---------------- CSR build ----------------
__global__ void count_deg(const int* __restrict__ dst, int* __restrict__ deg)
{
    int e = blockIdx.x * 256 + threadIdx.x;
    if (e < EST) atomicAdd(&deg[dst[e]], 1);
}

__global__ void scan_deg(const int* __restrict__ deg, int* __restrict__ offa)
{
    __shared__ int ts[1024];
    int t = threadIdx.x;
    int base = t * 8;
    int loc[8]; int s = 0;
    #pragma unroll
    for (int i = 0; i < 8; ++i) { loc[i] = s; s += deg[base + i]; }
    ts[t] = s;
    __syncthreads();
    for (int o = 1; o < 1024; o <<= 1) {
        int v = (t >= o) ? ts[t - o] : 0;
        __syncthreads();
        ts[t] += v;
        __syncthreads();
    }
    int prev = (t == 0) ? 0 : ts[t - 1];
    #pragma unroll
    for (int i = 0; i < 8; ++i) offa[base + i] = prev + loc[i];
    if (t == 1023) offa[8192] = ts[1023];
}

__global__ void scatter_csr(const int* __restrict__ dst, const int* __restrict__ offa,
                            int* __restrict__ cnt, int* __restrict__ csr)
{
    int e = blockIdx.x * 256 + threadIdx.x;
    if (e < EST) {
        int d = dst[e];
        int pos = offa[d] + atomicAdd(&cnt[d], 1);
        csr[pos] = e;
    }
}

// ---------------- RGAT0 aggregate ----------------
__global__ __launch_bounds__(256) void rgat_agg3(
    const float* __restrict__ h0, const float* __restrict__ h1,
    const int* __restrict__ offa, const int* __restrict__ csr,
    const int* __restrict__ src, const int* __restrict__ et,
    const float* __restrict__ logits, const float* __restrict__ bias,
    float* __restrict__ out)
{
    int n = blockIdx.x, t = threadIdx.x;
    int o0 = offa[n], deg = offa[n + 1] - o0;
    __shared__ float m[3], sden[3];
    __shared__ float al[64][3];
    __shared__ int esrc[64], erel[64];
    if (t < 3) {
        float mm = -1e30f;
        for (int i = 0; i < deg; ++i) mm = fmaxf(mm, logits[csr[o0 + i] * 3 + t]);
        float ss = 0.f;
        for (int i = 0; i < deg; ++i) ss += expf(logits[csr[o0 + i] * 3 + t] - mm);
        m[t] = mm; sden[t] = fmaxf(ss, 1e-16f);
    }
    __syncthreads();
    float acc0 = 0.f, acc1 = 0.f;
    for (int c0 = 0; c0 < deg; c0 += 64) {
        int cn = min(64, deg - c0);
        if (t < cn) { int e = csr[o0 + c0 + t]; esrc[t] = src[e]; erel[t] = et[e]; }
        if (t < cn * 3) {
            int ee = t / 3, hh = t % 3;
            int e = csr[o0 + c0 + ee];
            al[ee][hh] = expf(logits[e * 3 + hh] - m[hh]) / sden[hh];
        }
        __syncthreads();
        for (int i = 0; i < cn; ++i) {
            const float* hb = (erel[i] ? h1 : h0) + (size_t)esrc[i] * HO3;
            acc0 += al[i][t >> 7] * hb[t];
            if (t < 128) acc1 += al[i][(t + 256) >> 7] * hb[t + 256];
        }
        __syncthreads();
    }
    out[(size_t)n * HO3 + t] = tanhf(acc0 + bias[t]);
    if (t < 128) out[(size_t)n * HO3 + t + 256] = tanhf(acc1 + bias[t + 256]);
}

// ---------------- RGAT1 qi/kj ----------------
__global__ __launch_bounds__(128) void rgat_qk1(
    const float* __restrict__ h0, const float* __restrict__ h1,
    const float* __restrict__ q, const float* __restrict__ k,
    float* __restrict__ qi, float* __restrict__ kj)
{
    int n = blockIdx.x, t = threadIdx.x;
    float v0 = h0[(size_t)n * 128 + t], v1 = h1[(size_t)n * 128 + t];
    float p0 = v0 * q[t], p1 = v0 * k[t], p2 = v1 * q[t], p3 = v1 * k[t];
    __shared__ float red[2][4];
    for (int o = 32; o > 0; o >>= 1) {
        p0 += __shfl_down(p0, o, 64); p1 += __shfl_down(p1, o, 64);
        p2 += __shfl_down(p2, o, 64); p3 += __shfl_down(p3, o, 64);
    }
    if ((t & 63) == 0) { int w = t >> 6; red[w][0] = p0; red[w][1] = p1; red[w][2] = p2; red[w][3] = p3; }
    __syncthreads();
    if (t < 4) {
        float s = red[0][t] + red[1][t];
        if (t == 0) qi[n] = s;
        else if (t == 1) kj[n] = s;
        else if (t == 2) qi[NSTMT + n] = s;
        else kj[NSTMT + n] = s;
    }
}

__global__ void edge_logits1(const int* __restrict__ src, const int* __restrict__ dst,
                             const int* __restrict__ et,
                             const float* __restrict__ qi, const float* __restrict__ kj,
                             float* __restrict__ logits)
{
    int e = blockIdx.x * 256 + threadIdx.x;
    if (e >= EST) return;
    int r = et[e], s = src[e], d = dst[e];
    float x = qi[(size_t)r * NSTMT + d] + kj[(size_t)r * NSTMT + s];
    logits[e] = x > 0 ? x : 0.2f * x;
}

// ---------------- RGAT1 aggregate ----------------
__global__ __launch_bounds__(128) void rgat_agg1(
    const float* __restrict__ h0, const float* __restrict__ h1,
    const int* __restrict__ offa, const int* __restrict__ csr,
    const int* __restrict__ src, const int* __restrict__ et,
    const float* __restrict__ logits, const float* __restrict__ bias,
    float* __restrict__ out)
{
    int n = blockIdx.x, t = threadIdx.x;
    int o0 = offa[n], deg = offa[n + 1] - o0;
    __shared__ float m1, s1;
    __shared__ float al[64];
    __shared__ int esrc[64], erel[64];
    if (t == 0) {
        float mm = -1e30f;
        for (int i = 0; i < deg; ++i) mm = fmaxf(mm, logits[csr[o0 + i]]);
        float ss = 0.f;
        for (int i = 0; i < deg; ++i) ss += expf(logits[csr[o0 + i]] - mm);
        m1 = mm; s1 = fmaxf(ss, 1e-16f);
    }
    __syncthreads();
    float acc = 0.f;
    for (int c0 = 0; c0 < deg; c0 += 64) {
        int cn = min(64, deg - c0);
        if (t < cn) {
            int e = csr[o0 + c0 + t];
            esrc[t] = src[e]; erel[t] = et[e];
            al[t] = expf(logits[e] - m1) / s1;
        }
        __syncthreads();
        for (int i = 0; i < cn; ++i)
            acc += al[i] * ((erel[i] ? h1 : h0)[(size_t)esrc[i] * 128 + t]);
        __syncthreads();
    }
    out[(size_t)n * 128 + t] = tanhf(acc + bias[t]);
}

// ---------------- classifier ----------------
__global__ __launch_bounds__(128) void classifier(
    const float* __restrict__ x, const int* __restrict__ sel,
    const float* __restrict__ w1, const float* __restrict__ b1,
    const float* __restrict__ w2, const float* __restrict__ b2,
    float* __restrict__ out)
{
    __shared__ float row[128];
    __shared__ float t1[128];
    __shared__ float red[2];
    int b = blockIdx.x, t = threadIdx.x;
    int n = sel[b];
    row[t] = x[(size_t)n * 128 + t];
    __syncthreads();
    float acc = b1[t];
    for (int k = 0; k < 128; ++k) acc += row[k] * w1[k * 128 + t];
    t1[t] = fmaxf(acc, 0.f);
    __syncthreads();
    float p = t1[t] * w2[t];
    for (int o = 32; o > 0; o >>= 1) p += __shfl_down(p, o, 64);
    if ((t & 63) == 0) red[t >> 6] = p;
    __syncthreads();
    if (t == 0) {
        float z = red[0] + red[1] + b2[0];
        out[b] = 1.f / (1.f + expf(-z));
    }
}

// ---------------- workspace layout (bytes) ----------------
constexpr size_t OFF_HA     = 0;                       // 201326592
constexpr size_t OFF_BN0    = 201326592;               // ga0/be0/gw0/bw0: 4*768
constexpr size_t OFF_BN1    = OFF_BN0 + 3072;          // 4*256
constexpr size_t OFF_OLDROW = OFF_BN1 + 1024;          // 753664
constexpr size_t OFF_GATE   = OFF_OLDROW + 753664;     // 753664
constexpr size_t OFF_PARLOC = OFF_GATE + 753664;       // 753664
constexpr size_t OFF_HB     = OFF_PARLOC + 753664;     // 48234496 (psum0/psq0 alias here)
constexpr size_t OFF_XENC   = OFF_HB + 48234496;       // 4194304 (psum1/psq1 alias here)
constexpr size_t OFF_BNSUM  = OFF_XENC + 4194304;      // 1536
constexpr size_t OFF_BNSQ   = OFF_BNSUM + 1536;        // 1536
constexpr size_t WS_NEEDED  = OFF_BNSQ + 1536;
// stage-B aliases inside hA (dead after gemm_gather):
constexpr size_t OFF_H0R  = 0;
constexpr size_t OFF_H1R  = 12582912;
constexpr size_t OFF_OUT0 = 25165824;
constexpr size_t OFF_G0   = 37748736;
constexpr size_t OFF_G1   = 41943040;
constexpr size_t OFF_OUT1 = 46137344;
constexpr size_t OFF_QI3  = 50331648;
constexpr size_t OFF_KJ3  = 50528256;
constexpr size_t OFF_LG3  = 50724864;
constexpr size_t OFF_QI1  = 51118080;
constexpr size_t OFF_KJ1  = 51183616;
constexpr size_t OFF_LG1  = 51249152;
constexpr size_t OFF_DEG  = 51380224;
constexpr size_t OFF_OFFA = 51412992;
constexpr size_t OFF_CNT  = 51446016;
constexpr size_t OFF_CSR  = 51478784;

extern "C" void kernel_launch(void* const* d_in, const int* in_sizes, int n_in,
                              void* d_out, int out_size, void* d_ws, size_t ws_size,
                              hipStream_t stream)
{
    if (n_in < 41 || ws_size < WS_NEEDED) return;

    const float* ast_x    = (const float*)d_in[0];
    const int*   ast_src  = (const int*)d_in[1];
    const int*   stmt_src = (const int*)d_in[3];
    const int*   stmt_dst = (const int*)d_in[4];
    const int*   stmt_et  = (const int*)d_in[5];
    const int*   sel      = (const int*)d_in[6];
    const float* gat0_W    = (const float*)d_in[7];
    const float* gat0_asrc = (const float*)d_in[8];
    const float* gat0_adst = (const float*)d_in[9];
    const float* gat0_b    = (const float*)d_in[10];
    const float* bn0_g     = (const float*)d_in[11];
    const float* bn0_b     = (const float*)d_in[12];
    const float* pool0_w   = (const float*)d_in[13];
    const float* gat1_W    = (const float*)d_in[14];
    const float* gat1_asrc = (const float*)d_in[15];
    const float* gat1_adst = (const float*)d_in[16];
    const float* gat1_b    = (const float*)d_in[17];
    const float* bn1_g     = (const float*)d_in[18];
    const float* bn1_b     = (const float*)d_in[19];
    const float* pool1_w   = (const float*)d_in[20];
    const float* enc_w1    = (const float*)d_in[21];
    const float* enc_b1    = (const float*)d_in[22];
    const float* enc_w2    = (const float*)d_in[23];
    const float* enc_b2    = (const float*)d_in[24];
    const float* rgat0_W   = (const float*)d_in[25];
    const float* rgat0_q   = (const float*)d_in[26];
    const float* rgat0_k   = (const float*)d_in[27];
    const float* rgat0_b   = (const float*)d_in[28];
    const float* bnc0_g    = (const float*)d_in[29];
    const float* bnc0_b    = (const float*)d_in[30];
    const float* rgat1_W   = (const float*)d_in[31];
    const float* rgat1_q   = (const float*)d_in[32];
    const float* rgat1_k   = (const float*)d_in[33];
    const float* rgat1_b   = (const float*)d_in[34];
    const float* bnc1_g    = (const float*)d_in[35];
    const float* bnc1_b    = (const float*)d_in[36];
    const float* clf_w1    = (const float*)d_in[37];
    const float* clf_b1    = (const float*)d_in[38];
    const float* clf_w2    = (const float*)d_in[39];
    const float* clf_b2    = (const float*)d_in[40];

    char* ws = (char*)d_ws;
    float* hA     = (float*)(ws + OFF_HA);
    float* ga0    = (float*)(ws + OFF_BN0);
    float* be0    = ga0 + 192;
    float* gw0    = be0 + 192;
    float* bw0    = gw0 + 192;
    float* ga1    = (float*)(ws + OFF_BN1);
    float* be1    = ga1 + 64;
    float* gw1    = be1 + 64;
    float* bw1    = gw1 + 64;
    int*   oldrow = (int*)(ws + OFF_OLDROW);
    float* gate23 = (float*)(ws + OFF_GATE);
    int*   parloc = (int*)(ws + OFF_PARLOC);
    float* hB     = (float*)(ws + OFF_HB);
    float* psum0  = (float*)(ws + OFF_HB);              // alias (dead before hB written)
    float* psq0   = psum0 + 192 * 4096;
    float* xenc   = (float*)(ws + OFF_XENC);
    float* psum1  = (float*)(ws + OFF_XENC);            // alias (dead before xenc written)
    float* psq1   = psum1 + 64 * 8192;
    float* bnsum  = (float*)(ws + OFF_BNSUM);
    float* bnsq   = (float*)(ws + OFF_BNSQ);

    float* h0r  = (float*)(ws + OFF_H0R);
    float* h1r  = (float*)(ws + OFF_H1R);
    float* out0 = (float*)(ws + OFF_OUT0);
    float* g0   = (float*)(ws + OFF_G0);
    float* g1   = (float*)(ws + OFF_G1);
    float* out1 = (float*)(ws + OFF_OUT1);
    float* qi3  = (float*)(ws + OFF_QI3);
    float* kj3  = (float*)(ws + OFF_KJ3);
    float* lg3  = (float*)(ws + OFF_LG3);
    float* qi1  = (float*)(ws + OFF_QI1);
    float* kj1  = (float*)(ws + OFF_KJ1);
    float* lg1  = (float*)(ws + OFF_LG1);
    int*   deg  = (int*)(ws + OFF_DEG);
    int*   offa = (int*)(ws + OFF_OFFA);
    int*   cnt  = (int*)(ws + OFF_CNT);
    int*   csr  = (int*)(ws + OFF_CSR);

    // ---- Stage A: statement encoder ----
    fused_gat0<<<4096, 256, 0, stream>>>(ast_x, gat0_W, ast_src, gat0_asrc, gat0_adst,
                                         gat0_b, hA, psum0, psq0);
    bn_finalize<<<192, 256, 0, stream>>>(psum0, psq0, 4096, (float)N0,
                                         bn0_g, bn0_b, pool0_w, ga0, be0, gw0, bw0);
    score_topk0<<<G, 256, 0, stream>>>(hA, ast_src, gw0, bw0, pool0_w,
                                       oldrow, gate23, parloc);
    gemm_gather<<<N1 / 64, 256, 0, stream>>>(hA, gat1_W, hB, oldrow, gate23, ga0, be0);
    gat1_att_bn<<<G, 64, 0, stream>>>(hB, parloc, gat1_asrc, gat1_adst, gat1_b,
                                      psum1, psq1);
    bn_finalize<<<64, 256, 0, stream>>>(psum1, psq1, 8192, (float)N1,
                                        bn1_g, bn1_b, pool1_w, ga1, be1, gw1, bw1);
    pool1_mlp<<<G, 128, 0, stream>>>(hB, gw1, bw1, pool1_w, ga1, be1,
                                     enc_w1, enc_b1, enc_w2, enc_b2, xenc);

    // ---- Stage B: statement classifier ----
    gemm_nn<<<dim3(NSTMT / 64, HO3 / 64), 256, 0, stream>>>(xenc, rgat0_W, h0r, NSTMT, HO3, ENC);
    gemm_nn<<<dim3(NSTMT / 64, HO3 / 64), 256, 0, stream>>>(xenc, rgat0_W + (size_t)ENC * HO3, h1r, NSTMT, HO3, ENC);
    rgat_qk3<<<NSTMT, 256, 0, stream>>>(h0r, h1r, rgat0_q, rgat0_k, qi3, kj3);
    edge_logits3<<<EST / 256, 256, 0, stream>>>(stmt_src, stmt_dst, stmt_et, qi3, kj3, lg3);
    hipMemsetAsync(deg, 0, 32768, stream);
    hipMemsetAsync(cnt, 0, 32768, stream);
    count_deg<<<EST / 256, 256, 0, stream>>>(stmt_dst, deg);
    scan_deg<<<1, 1024, 0, stream>>>(deg, offa);
    scatter_csr<<<EST / 256, 256, 0, stream>>>(stmt_dst, offa, cnt, csr);
    rgat_agg3<<<NSTMT, 256, 0, stream>>>(h0r, h1r, offa, csr, stmt_src, stmt_et, lg3, rgat0_b, out0);
    hipMemsetAsync(bnsum, 0, 3072, stream);
    bn_stats<<<256, HO3, 0, stream>>>(out0, NSTMT, bnsum, bnsq);
    bn_apply<<<256, HO3, 0, stream>>>(out0, NSTMT, bnsum, bnsq, bnc0_g, bnc0_b);
    gemm_nn<<<dim3(NSTMT / 64, HOUT / 64), 256, 0, stream>>>(out0, rgat1_W, g0, NSTMT, HOUT, HO3);
    gemm_nn<<<dim3(NSTMT / 64, HOUT / 64), 256, 0, stream>>>(out0, rgat1_W + (size_t)HO3 * HOUT, g1, NSTMT, HOUT, HO3);
    rgat_qk1<<<NSTMT, 128, 0, stream>>>(g0, g1, rgat1_q, rgat1_k, qi1, kj1);
    edge_logits1<<<EST / 256, 256, 0, stream>>>(stmt_src, stmt_dst, stmt_et, qi1, kj1, lg1);
    rgat_agg1<<<NSTMT, 128, 0, stream>>>(g0, g1, offa, csr, stmt_src, stmt_et, lg1, rgat1_b, out1);
    hipMemsetAsync(bnsum, 0, 3072, stream);
    bn_stats<<<256, HOUT, 0, stream>>>(out1, NSTMT, bnsum, bnsq);
    bn_apply<<<256, HOUT, 0, stream>>>(out1, NSTMT, bnsum, bnsq, bnc1_g, bnc1_b);
    classifier<<<NSEL, 128, 0, stream>>>(out1, sel, clf_w1, clf_b1, clf_w2, clf_b2, (float*)d_out);
}

// Round 3
// 931.841 us; speedup vs baseline: 1.3544x; 1.0566x over previous
//
#include <hip/hip_runtime.h>
#include <cstddef>
#include <cstdint>

// ---------------- problem constants ----------------
constexpr int G      = 8192;
constexpr int NAST   = 32;
constexpr int N0     = G * NAST;    // 262144
constexpr int D_EMB  = 128;
constexpr int C0     = 192;         // 3 * H_IN
constexpr int H_IN   = 64;
constexpr int K0     = 23;          // ceil(0.7*32)
constexpr int N1     = G * K0;      // 188416
constexpr int K1     = 12;          // ceil(0.5*23)
constexpr int ENC    = 128;
constexpr int NSTMT  = 8192;
constexpr int EST    = 32768;
constexpr int HO3    = 384;
constexpr int HOUT   = 128;
constexpr int NSEL   = 4096;

// =====================================================================
// Fused GAT0: per-block = 2 AST graphs (64 rows) x 192 cols, K=128.
// 192 threads, 8x8 register tiles. GEMM -> attention -> +bias -> tanh
// -> write hA + coalesced per-block BN partials.
// =====================================================================
__global__ __launch_bounds__(192) void fused_gat0(
    const float* __restrict__ X, const float* __restrict__ W,
    const int* __restrict__ ast_src,
    const float* __restrict__ asrc_w, const float* __restrict__ adst_w,
    const float* __restrict__ bias,
    float* __restrict__ out, float* __restrict__ psum, float* __restrict__ psq)
{
    __shared__ float smem[13376];      // 53504 B
    float* As = smem;                  // [32][68] k-major
    float* Bs = smem + 2176;           // [32][200] k-major
    int tid = threadIdx.x;
    int b = blockIdx.x;
    int row0 = b * 64;
    int tm = tid / 24;                 // 0..7 : row group (8 rows)
    int tn = tid % 24;                 // 0..23: col group (8 cols)

    float acc[8][8] = {};

    for (int kt = 0; kt < 128; kt += 32) {
        // stage A tile: 64 rows x 32 k  (scatter to k-major)
        for (int i = tid; i < 512; i += 192) {
            int r = i & 63, q = i >> 6;
            float4 v = *(const float4*)(X + (size_t)(row0 + r) * 128 + kt + q * 4);
            As[(q * 4 + 0) * 68 + r] = v.x;
            As[(q * 4 + 1) * 68 + r] = v.y;
            As[(q * 4 + 2) * 68 + r] = v.z;
            As[(q * 4 + 3) * 68 + r] = v.w;
        }
        // stage B tile: 32 k x 192 n
        for (int i = tid; i < 1536; i += 192) {
            int k = i / 48, c4 = (i % 48) * 4;
            *(float4*)&Bs[k * 200 + c4] = *(const float4*)(W + (size_t)(kt + k) * 192 + c4);
        }
        __syncthreads();
        #pragma unroll 4
        for (int kk = 0; kk < 32; ++kk) {
            float4 a0 = *(const float4*)&As[kk * 68 + tm * 8];
            float4 a1 = *(const float4*)&As[kk * 68 + tm * 8 + 4];
            float4 b0 = *(const float4*)&Bs[kk * 200 + tn * 8];
            float4 b1 = *(const float4*)&Bs[kk * 200 + tn * 8 + 4];
            float a_[8] = {a0.x, a0.y, a0.z, a0.w, a1.x, a1.y, a1.z, a1.w};
            float b_[8] = {b0.x, b0.y, b0.z, b0.w, b1.x, b1.y, b1.z, b1.w};
            #pragma unroll
            for (int i = 0; i < 8; ++i)
                #pragma unroll
                for (int j = 0; j < 8; ++j)
                    acc[i][j] += a_[i] * b_[j];
        }
        __syncthreads();
    }

    // ---- phase 2: attention epilogue ----
    float* Cs  = smem;                 // [64][196]
    float* as_ = smem + 12544;         // [64][3]
    float* ad_ = as_ + 192;
    float* aS  = ad_ + 192;
    float* aP  = aS + 192;
    int*  parl = (int*)(aP + 192);     // [64]

    #pragma unroll
    for (int i = 0; i < 8; ++i) {
        *(float4*)&Cs[(tm * 8 + i) * 196 + tn * 8]     = *(float4*)&acc[i][0];
        *(float4*)&Cs[(tm * 8 + i) * 196 + tn * 8 + 4] = *(float4*)&acc[i][4];
    }
    if (tid < 62) {
        int q = tid / 31, j = tid % 31 + 1;
        int g = 2 * b + q;
        parl[q * 32 + j] = ast_src[(size_t)g * 31 + j - 1] - g * 32 + q * 32;
    }
    if (tid < 2) parl[tid * 32] = -1;
    __syncthreads();

    for (int task = tid; task < 384; task += 192) {
        int r = task / 6, q6 = task % 6, hh = q6 >> 1, sd = q6 & 1;
        const float* w = (sd ? adst_w : asrc_w) + hh * 64;
        const float* crow = &Cs[r * 196 + hh * 64];
        float s = 0.f;
        for (int c = 0; c < 64; ++c) s += crow[c] * w[c];
        (sd ? ad_ : as_)[r * 3 + hh] = s;
    }
    __syncthreads();
    if (tid < 192) {
        int r = tid / 3, hh = tid % 3, p = parl[r];
        if (p < 0) { aS[r * 3 + hh] = 1.f; aP[r * 3 + hh] = 0.f; }
        else {
            float ls = as_[r * 3 + hh] + ad_[r * 3 + hh]; ls = ls > 0 ? ls : 0.2f * ls;
            float lp = as_[p * 3 + hh] + ad_[r * 3 + hh]; lp = lp > 0 ? lp : 0.2f * lp;
            float m = fmaxf(ls, lp);
            float es = expf(ls - m), ep = expf(lp - m);
            float inv = 1.f / (es + ep);
            aS[r * 3 + hh] = es * inv; aP[r * 3 + hh] = ep * inv;
        }
    }
    __syncthreads();
    {
        int j = tid, hh = j >> 6;
        float bj = bias[j];
        float s = 0.f, s2 = 0.f;
        for (int r = 0; r < 64; ++r) {
            int p = parl[r];
            float v = aS[r * 3 + hh] * Cs[r * 196 + j];
            if (p >= 0) v += aP[r * 3 + hh] * Cs[p * 196 + j];
            v = tanhf(v + bj);
            out[(size_t)(row0 + r) * 192 + j] = v;
            s += v; s2 += v * v;
        }
        psum[(size_t)b * 192 + j] = s;   // coalesced [block][col]
        psq [(size_t)b * 192 + j] = s2;
    }
}

// =====================================================================
// BN finalize: column j of [nb][C] partials -> ga/be + folded gw/bw.
// =====================================================================
__global__ __launch_bounds__(256) void bn_finalize(
    const float* __restrict__ psum, const float* __restrict__ psq, int nb, int C, float R,
    const float* __restrict__ gamma, const float* __restrict__ beta,
    const float* __restrict__ w,
    float* __restrict__ ga, float* __restrict__ be,
    float* __restrict__ gw, float* __restrict__ bw)
{
    int j = blockIdx.x, t = threadIdx.x;
    float s = 0.f, s2 = 0.f;
    for (int i = t; i < nb; i += 256) {
        s  += psum[(size_t)i * C + j];
        s2 += psq [(size_t)i * C + j];
    }
    __shared__ float r1[4], r2[4];
    for (int o = 32; o > 0; o >>= 1) { s += __shfl_down(s, o, 64); s2 += __shfl_down(s2, o, 64); }
    if ((t & 63) == 0) { r1[t >> 6] = s; r2[t >> 6] = s2; }
    __syncthreads();
    if (t == 0) {
        float S = r1[0] + r1[1] + r1[2] + r1[3];
        float S2 = r2[0] + r2[1] + r2[2] + r2[3];
        float mu = S / R, var = S2 / R - mu * mu;
        float inv = 1.f / sqrtf(var + 1e-5f);
        float gaj = gamma[j] * inv, bej = beta[j] - mu * gaj;
        ga[j] = gaj; be[j] = bej; gw[j] = gaj * w[j]; bw[j] = bej * w[j];
    }
}

// =====================================================================
// Score + TopK(32->23) + parent remap. Reads raw hA once.
// =====================================================================
__global__ __launch_bounds__(256) void score_topk0(
    const float* __restrict__ hA, const int* __restrict__ ast_src,
    const float* __restrict__ gw, const float* __restrict__ bw,
    const float* __restrict__ w,
    int* __restrict__ oldrow, float* __restrict__ gate23, int* __restrict__ parloc)
{
    __shared__ float swv[192];
    __shared__ float sc[32];
    __shared__ int nid[32];
    __shared__ float wparts[4], bparts[4];
    int g = blockIdx.x, t = threadIdx.x;
    if (t < 192) swv[t] = gw[t];
    float ws = (t < 192) ? w[t] * w[t] : 0.f;
    float bs = (t < 192) ? bw[t] : 0.f;
    for (int o = 32; o > 0; o >>= 1) { ws += __shfl_down(ws, o, 64); bs += __shfl_down(bs, o, 64); }
    if ((t & 63) == 0) { wparts[t >> 6] = ws; bparts[t >> 6] = bs; }
    __syncthreads();
    float invn = 1.f / sqrtf(wparts[0] + wparts[1] + wparts[2] + wparts[3]);
    float sb = bparts[0] + bparts[1] + bparts[2] + bparts[3];

    int r = t >> 3, j0 = (t & 7) * 24;
    const float4* row4 = (const float4*)(hA + ((size_t)g * 32 + r) * 192 + j0);
    const float4* sw4 = (const float4*)(swv + j0);
    float s = 0.f;
    #pragma unroll
    for (int u = 0; u < 6; ++u) {
        float4 a = row4[u], bv = sw4[u];
        s += a.x * bv.x + a.y * bv.y + a.z * bv.z + a.w * bv.w;
    }
    for (int o = 4; o > 0; o >>= 1) s += __shfl_down(s, o, 8);
    if ((t & 7) == 0) sc[r] = (s + sb) * invn;
    __syncthreads();
    if (t < 32) {
        float v = sc[t]; int rank = 0;
        for (int j = 0; j < 32; ++j) rank += (sc[j] > v) || (sc[j] == v && j < t);
        nid[t] = (rank < 23) ? rank : -1;
    }
    __syncthreads();
    if (t < 32 && nid[t] >= 0) {
        int rank = nid[t];
        oldrow[g * 23 + rank] = g * 32 + t;
        gate23[g * 23 + rank] = tanhf(sc[t]);
        int pl = -1;
        if (t > 0) {
            int p = ast_src[(size_t)g * 31 + t - 1] - g * 32;
            pl = nid[p];
        }
        parloc[g * 23 + rank] = pl;
    }
}

// =====================================================================
// Gather-GEMM: hB[N1,64] = relu((hA[old]*ga+be)*gate) @ gat1_W[192,64]
// =====================================================================
__global__ __launch_bounds__(256) void gemm_gather(
    const float* __restrict__ A, const float* __restrict__ B, float* __restrict__ C,
    const int* __restrict__ rowmap, const float* __restrict__ gate,
    const float* __restrict__ ga, const float* __restrict__ be)
{
    __shared__ float As[16 * 68];
    __shared__ float Bs[16 * 68];
    __shared__ float gas[192], bes[192];
    int tid = threadIdx.x, bm = blockIdx.x;
    if (tid < 192) { gas[tid] = ga[tid]; bes[tid] = be[tid]; }
    int arow = tid >> 2, aks = (tid & 3) * 4;
    int brow = tid >> 4, bns = (tid & 15) * 4;
    int tm = tid >> 4, tn = tid & 15;
    float acc[4][4] = {};
    int grow = bm * 64 + arow;
    int old = rowmap[grow];
    float gt = gate[grow];
    const float* ap = A + (size_t)old * 192;
    __syncthreads();
    for (int kt = 0; kt < 192; kt += 16) {
        float4 av = *(const float4*)(ap + kt + aks);
        int kb = kt + aks;
        av.x = fmaxf((av.x * gas[kb + 0] + bes[kb + 0]) * gt, 0.f);
        av.y = fmaxf((av.y * gas[kb + 1] + bes[kb + 1]) * gt, 0.f);
        av.z = fmaxf((av.z * gas[kb + 2] + bes[kb + 2]) * gt, 0.f);
        av.w = fmaxf((av.w * gas[kb + 3] + bes[kb + 3]) * gt, 0.f);
        As[(aks + 0) * 68 + arow] = av.x;
        As[(aks + 1) * 68 + arow] = av.y;
        As[(aks + 2) * 68 + arow] = av.z;
        As[(aks + 3) * 68 + arow] = av.w;
        *(float4*)&Bs[brow * 68 + bns] = *(const float4*)(B + (size_t)(kt + brow) * 64 + bns);
        __syncthreads();
        #pragma unroll
        for (int kk = 0; kk < 16; ++kk) {
            float4 a4 = *(const float4*)&As[kk * 68 + (tm << 2)];
            float4 b4 = *(const float4*)&Bs[kk * 68 + (tn << 2)];
            float a_[4] = {a4.x, a4.y, a4.z, a4.w};
            float b_[4] = {b4.x, b4.y, b4.z, b4.w};
            #pragma unroll
            for (int i = 0; i < 4; ++i)
                #pragma unroll
                for (int j = 0; j < 4; ++j)
                    acc[i][j] += a_[i] * b_[j];
        }
        __syncthreads();
    }
    #pragma unroll
    for (int i = 0; i < 4; ++i) {
        int rr = bm * 64 + (tm << 2) + i;
        float4 o = {acc[i][0], acc[i][1], acc[i][2], acc[i][3]};
        *(float4*)(C + (size_t)rr * 64 + (tn << 2)) = o;
    }
}

// =====================================================================
// GAT1 attention (in place on hB) + tanh + BN1 partials. 64 threads.
// =====================================================================
__global__ __launch_bounds__(64) void gat1_att_bn(
    float* __restrict__ h, const int* __restrict__ parloc,
    const float* __restrict__ aw_s, const float* __restrict__ aw_d,
    const float* __restrict__ bias,
    float* __restrict__ psum, float* __restrict__ psq)
{
    __shared__ float hs[23 * 65];
    __shared__ float as_[23], ad_[23], aS[23], aP[23];
    __shared__ int parl[23];
    int g = blockIdx.x, t = threadIdx.x;
    float* base = h + (size_t)g * 23 * 64;
    for (int r = 0; r < 23; ++r) hs[r * 65 + t] = base[r * 64 + t];
    if (t < 23) parl[t] = parloc[g * 23 + t];
    __syncthreads();
    if (t < 46) {
        int r = t >> 1, sd = t & 1;
        const float* w = sd ? aw_d : aw_s;
        const float* row = &hs[r * 65];
        float s = 0.f;
        for (int c = 0; c < 64; ++c) s += row[c] * w[c];
        (sd ? ad_ : as_)[r] = s;
    }
    __syncthreads();
    if (t < 23) {
        int p = parl[t];
        if (p < 0) { aS[t] = 1.f; aP[t] = 0.f; }
        else {
            float ls = as_[t] + ad_[t]; ls = ls > 0 ? ls : 0.2f * ls;
            float lp = as_[p] + ad_[t]; lp = lp > 0 ? lp : 0.2f * lp;
            float m = fmaxf(ls, lp);
            float es = expf(ls - m), ep = expf(lp - m);
            float inv = 1.f / (es + ep);
            aS[t] = es * inv; aP[t] = ep * inv;
        }
    }
    __syncthreads();
    float bj = bias[t], s = 0.f, s2 = 0.f;
    for (int r = 0; r < 23; ++r) {
        int p = parl[r];
        float v = aS[r] * hs[r * 65 + t];
        if (p >= 0) v += aP[r] * hs[p * 65 + t];
        v = tanhf(v + bj);
        base[r * 64 + t] = v;
        s += v; s2 += v * v;
    }
    psum[(size_t)g * 64 + t] = s;    // coalesced [g][col]
    psq [(size_t)g * 64 + t] = s2;
}

// =====================================================================
// Score1 + TopK(23->12) + gated-BN maxpool + relu + encoder MLP -> xenc
// =====================================================================
__global__ __launch_bounds__(128) void pool1_mlp(
    const float* __restrict__ h,
    const float* __restrict__ gw, const float* __restrict__ bw,
    const float* __restrict__ w,
    const float* __restrict__ ga, const float* __restrict__ be,
    const float* __restrict__ w1, const float* __restrict__ b1,
    const float* __restrict__ w2, const float* __restrict__ b2,
    float* __restrict__ xenc)
{
    __shared__ float hs[23 * 65];
    __shared__ float sc[23];
    __shared__ int keep[23];
    __shared__ float feat[64], t1[64];
    __shared__ float consts[2];
    int g = blockIdx.x, t = threadIdx.x;
    const float* base = h + (size_t)g * 23 * 64;
    {
        int c = t & 63;
        for (int r = t >> 6; r < 23; r += 2) hs[r * 65 + c] = base[r * 64 + c];
    }
    if (t < 64) {
        float ws = w[t] * w[t], bs = bw[t];
        for (int o = 32; o > 0; o >>= 1) { ws += __shfl_down(ws, o, 64); bs += __shfl_down(bs, o, 64); }
        if (t == 0) { consts[0] = 1.f / sqrtf(ws); consts[1] = bs; }
    }
    __syncthreads();
    if (t < 23) {
        const float* row = &hs[t * 65];
        float s = 0.f;
        for (int c = 0; c < 64; ++c) s += row[c] * gw[c];
        sc[t] = (s + consts[1]) * consts[0];
    }
    __syncthreads();
    if (t < 23) {
        float v = sc[t]; int rank = 0;
        for (int j = 0; j < 23; ++j) rank += (sc[j] > v) || (sc[j] == v && j < t);
        keep[t] = rank < 12;
    }
    __syncthreads();
    if (t < 23) sc[t] = tanhf(sc[t]);
    __syncthreads();
    if (t < 64) {
        float m = -1e30f, gac = ga[t], bec = be[t];
        for (int r = 0; r < 23; ++r)
            if (keep[r]) m = fmaxf(m, (hs[r * 65 + t] * gac + bec) * sc[r]);
        feat[t] = fmaxf(m, 0.f);
    }
    __syncthreads();
    if (t < 64) {
        float acc = b1[t];
        for (int c = 0; c < 64; ++c) acc += feat[c] * w1[c * 64 + t];
        t1[t] = fmaxf(acc, 0.f);
    }
    __syncthreads();
    float acc = b2[t];
    for (int j = 0; j < 64; ++j) acc += t1[j] * w2[j * 128 + t];
    xenc[(size_t)g * 128 + t] = acc;
}

// =====================================================================
// Generic tiled GEMM (stage B)
// =====================================================================
__global__ __launch_bounds__(256) void gemm_nn(
    const float* __restrict__ A, const float* __restrict__ B, float* __restrict__ C,
    int M, int N, int K)
{
    __shared__ float As[16 * 68];
    __shared__ float Bs[16 * 68];
    int tid = threadIdx.x;
    int bm = blockIdx.x, bn = blockIdx.y;
    int arow = tid >> 2, aks = (tid & 3) * 4;
    int brow = tid >> 4, bns = (tid & 15) * 4;
    int tm = tid >> 4, tn = tid & 15;
    float acc[4][4] = {};
    const float* ap = A + (size_t)(bm * 64 + arow) * K;
    for (int kt = 0; kt < K; kt += 16) {
        float4 av = *(const float4*)(ap + kt + aks);
        As[(aks + 0) * 68 + arow] = av.x;
        As[(aks + 1) * 68 + arow] = av.y;
        As[(aks + 2) * 68 + arow] = av.z;
        As[(aks + 3) * 68 + arow] = av.w;
        *(float4*)&Bs[brow * 68 + bns] = *(const float4*)(B + (size_t)(kt + brow) * N + bn * 64 + bns);
        __syncthreads();
        #pragma unroll
        for (int kk = 0; kk < 16; ++kk) {
            float4 a4 = *(const float4*)&As[kk * 68 + (tm << 2)];
            float4 b4 = *(const float4*)&Bs[kk * 68 + (tn << 2)];
            float a_[4] = {a4.x, a4.y, a4.z, a4.w};
            float b_[4] = {b4.x, b4.y, b4.z, b4.w};
            #pragma unroll
            for (int i = 0; i < 4; ++i)
                #pragma unroll
                for (int j = 0; j < 4; ++j)
                    acc[i][j] += a_[i] * b_[j];
        }
        __syncthreads();
    }
    #pragma unroll
    for (int i = 0; i < 4; ++i) {
        int r = bm * 64 + (tm << 2) + i;
        float4 o = {acc[i][0], acc[i][1], acc[i][2], acc[i][3]};
        *(float4*)(C + (size_t)r * N + bn * 64 + (tn << 2)) = o;
    }
}

// ---------------- BatchNorm (stage B) ----------------
__global__ void bn_stats(const float* __restrict__ X, int R,
                         float* __restrict__ sum, float* __restrict__ sumsq)
{
    int t = threadIdx.x;
    int C = blockDim.x;
    float s = 0.f, s2 = 0.f;
    for (int r = blockIdx.x; r < R; r += gridDim.x) {
        float v = X[(size_t)r * C + t];
        s += v; s2 += v * v;
    }
    atomicAdd(&sum[t], s);
    atomicAdd(&sumsq[t], s2);
}

__global__ void bn_apply(float* __restrict__ X, int R,
                         const float* __restrict__ sum, const float* __restrict__ sumsq,
                         const float* __restrict__ gam, const float* __restrict__ bet)
{
    int t = threadIdx.x;
    int C = blockDim.x;
    float invR = 1.f / (float)R;
    float mu = sum[t] * invR;
    float var = sumsq[t] * invR - mu * mu;
    float inv = 1.f / sqrtf(var + 1e-5f);
    float ga = gam[t] * inv;
    float be = bet[t] - mu * ga;
    for (int r = blockIdx.x; r < R; r += gridDim.x) {
        size_t idx = (size_t)r * C + t;
        X[idx] = X[idx] * ga + be;
    }
}

// ---------------- RGAT qi/kj precompute (3 heads) ----------------
__global__ __launch_bounds__(256) void rgat_qk3(
    const float* __restrict__ h0, const float* __restrict__ h1,
    const float* __restrict__ q, const float* __restrict__ k,
    float* __restrict__ qi, float* __restrict__ kj)
{
    int n = blockIdx.x, t = threadIdx.x;
    float p[12] = {};
    for (int d = t; d < HO3; d += 256) {
        float v0 = h0[(size_t)n * HO3 + d], v1 = h1[(size_t)n * HO3 + d];
        #pragma unroll
        for (int hh = 0; hh < 3; ++hh) {
            float qw = q[d * 3 + hh], kw = k[d * 3 + hh];
            p[hh]     += v0 * qw;  p[3 + hh] += v0 * kw;
            p[6 + hh] += v1 * qw;  p[9 + hh] += v1 * kw;
        }
    }
    __shared__ float red[4][12];
    #pragma unroll
    for (int i = 0; i < 12; ++i) {
        float x = p[i];
        for (int o = 32; o > 0; o >>= 1) x += __shfl_down(x, o, 64);
        if ((t & 63) == 0) red[t >> 6][i] = x;
    }
    __syncthreads();
    if (t < 12) {
        float s = red[0][t] + red[1][t] + red[2][t] + red[3][t];
        int rel = t / 6, rem = t % 6, isk = rem / 3, hh = rem % 3;
        float* dst = isk ? kj : qi;
        dst[((size_t)rel * NSTMT + n) * 3 + hh] = s;
    }
}

__global__ void edge_logits3(const int* __restrict__ src, const int* __restrict__ dst,
                             const int* __restrict__ et,
                             const float* __restrict__ qi, const float* __restrict__ kj,
                             float* __restrict__ logits)
{
    int e = blockIdx.x * 256 + threadIdx.x;
    if (e >= EST) return;
    int r = et[e], s = src[e], d = dst[e];
    #pragma unroll
    for (int hh = 0; hh < 3; ++hh) {
        float x = qi[((size_t)r * NSTMT + d) * 3 + hh] + kj[((size_t)r * NSTMT + s) * 3 + hh];
        logits[e * 3 + hh] = x > 0 ? x : 0.2f * x;
    }
}

// ---------------- CSR build ----------------
__global__ void count_deg(const int* __restrict__ dst, int* __restrict__ deg)
{
    int e = blockIdx.x * 256 + threadIdx.x;
    if (e < EST) atomicAdd(&deg[dst[e]], 1);
}

__global__ void scan_deg(const int* __restrict__ deg, int* __restrict__ offa)
{
    __shared__ int ts[1024];
    int t = threadIdx.x;
    int base = t * 8;
    int loc[8]; int s = 0;
    #pragma unroll
    for (int i = 0; i < 8; ++i) { loc[i] = s; s += deg[base + i]; }
    ts[t] = s;
    __syncthreads();
    for (int o = 1; o < 1024; o <<= 1) {
        int v = (t >= o) ? ts[t - o] : 0;
        __syncthreads();
        ts[t] += v;
        __syncthreads();
    }
    int prev = (t == 0) ? 0 : ts[t - 1];
    #pragma unroll
    for (int i = 0; i < 8; ++i) offa[base + i] = prev + loc[i];
    if (t == 1023) offa[8192] = ts[1023];
}

__global__ void scatter_csr(const int* __restrict__ dst, const int* __restrict__ offa,
                            int* __restrict__ cnt, int* __restrict__ csr)
{
    int e = blockIdx.x * 256 + threadIdx.x;
    if (e < EST) {
        int d = dst[e];
        int pos = offa[d] + atomicAdd(&cnt[d], 1);
        csr[pos] = e;
    }
}

// ---------------- RGAT0 aggregate ----------------
__global__ __launch_bounds__(256) void rgat_agg3(
    const float* __restrict__ h0, const float* __restrict__ h1,
    const int* __restrict__ offa, const int* __restrict__ csr,
    const int* __restrict__ src, const int* __restrict__ et,
    const float* __restrict__ logits, const float* __restrict__ bias,
    float* __restrict__ out)
{
    int n = blockIdx.x, t = threadIdx.x;
    int o0 = offa[n], deg = offa[n + 1] - o0;
    __shared__ float m[3], sden[3];
    __shared__ float al[64][3];
    __shared__ int esrc[64], erel[64];
    if (t < 3) {
        float mm = -1e30f;
        for (int i = 0; i < deg; ++i) mm = fmaxf(mm, logits[csr[o0 + i] * 3 + t]);
        float ss = 0.f;
        for (int i = 0; i < deg; ++i) ss += expf(logits[csr[o0 + i] * 3 + t] - mm);
        m[t] = mm; sden[t] = fmaxf(ss, 1e-16f);
    }
    __syncthreads();
    float acc0 = 0.f, acc1 = 0.f;
    for (int c0 = 0; c0 < deg; c0 += 64) {
        int cn = min(64, deg - c0);
        if (t < cn) { int e = csr[o0 + c0 + t]; esrc[t] = src[e]; erel[t] = et[e]; }
        if (t < cn * 3) {
            int ee = t / 3, hh = t % 3;
            int e = csr[o0 + c0 + ee];
            al[ee][hh] = expf(logits[e * 3 + hh] - m[hh]) / sden[hh];
        }
        __syncthreads();
        for (int i = 0; i < cn; ++i) {
            const float* hb = (erel[i] ? h1 : h0) + (size_t)esrc[i] * HO3;
            acc0 += al[i][t >> 7] * hb[t];
            if (t < 128) acc1 += al[i][(t + 256) >> 7] * hb[t + 256];
        }
        __syncthreads();
    }
    out[(size_t)n * HO3 + t] = tanhf(acc0 + bias[t]);
    if (t < 128) out[(size_t)n * HO3 + t + 256] = tanhf(acc1 + bias[t + 256]);
}

// ---------------- RGAT1 qi/kj ----------------
__global__ __launch_bounds__(128) void rgat_qk1(
    const float* __restrict__ h0, const float* __restrict__ h1,
    const float* __restrict__ q, const float* __restrict__ k,
    float* __restrict__ qi, float* __restrict__ kj)
{
    int n = blockIdx.x, t = threadIdx.x;
    float v0 = h0[(size_t)n * 128 + t], v1 = h1[(size_t)n * 128 + t];
    float p0 = v0 * q[t], p1 = v0 * k[t], p2 = v1 * q[t], p3 = v1 * k[t];
    __shared__ float red[2][4];
    for (int o = 32; o > 0; o >>= 1) {
        p0 += __shfl_down(p0, o, 64); p1 += __shfl_down(p1, o, 64);
        p2 += __shfl_down(p2, o, 64); p3 += __shfl_down(p3, o, 64);
    }
    if ((t & 63) == 0) { int w = t >> 6; red[w][0] = p0; red[w][1] = p1; red[w][2] = p2; red[w][3] = p3; }
    __syncthreads();
    if (t < 4) {
        float s = red[0][t] + red[1][t];
        if (t == 0) qi[n] = s;
        else if (t == 1) kj[n] = s;
        else if (t == 2) qi[NSTMT + n] = s;
        else kj[NSTMT + n] = s;
    }
}

__global__ void edge_logits1(const int* __restrict__ src, const int* __restrict__ dst,
                             const int* __restrict__ et,
                             const float* __restrict__ qi, const float* __restrict__ kj,
                             float* __restrict__ logits)
{
    int e = blockIdx.x * 256 + threadIdx.x;
    if (e >= EST) return;
    int r = et[e], s = src[e], d = dst[e];
    float x = qi[(size_t)r * NSTMT + d] + kj[(size_t)r * NSTMT + s];
    logits[e] = x > 0 ? x : 0.2f * x;
}

// ---------------- RGAT1 aggregate ----------------
__global__ __launch_bounds__(128) void rgat_agg1(
    const float* __restrict__ h0, const float* __restrict__ h1,
    const int* __restrict__ offa, const int* __restrict__ csr,
    const int* __restrict__ src, const int* __restrict__ et,
    const float* __restrict__ logits, const float* __restrict__ bias,
    float* __restrict__ out)
{
    int n = blockIdx.x, t = threadIdx.x;
    int o0 = offa[n], deg = offa[n + 1] - o0;
    __shared__ float m1, s1;
    __shared__ float al[64];
    __shared__ int esrc[64], erel[64];
    if (t == 0) {
        float mm = -1e30f;
        for (int i = 0; i < deg; ++i) mm = fmaxf(mm, logits[csr[o0 + i]]);
        float ss = 0.f;
        for (int i = 0; i < deg; ++i) ss += expf(logits[csr[o0 + i]] - mm);
        m1 = mm; s1 = fmaxf(ss, 1e-16f);
    }
    __syncthreads();
    float acc = 0.f;
    for (int c0 = 0; c0 < deg; c0 += 64) {
        int cn = min(64, deg - c0);
        if (t < cn) {
            int e = csr[o0 + c0 + t];
            esrc[t] = src[e]; erel[t] = et[e];
            al[t] = expf(logits[e] - m1) / s1;
        }
        __syncthreads();
        for (int i = 0; i < cn; ++i)
            acc += al[i] * ((erel[i] ? h1 : h0)[(size_t)esrc[i] * 128 + t]);
        __syncthreads();
    }
    out[(size_t)n * 128 + t] = tanhf(acc + bias[t]);
}

// ---------------- classifier ----------------
__global__ __launch_bounds__(128) void classifier(
    const float* __restrict__ x, const int* __restrict__ sel,
    const float* __restrict__ w1, const float* __restrict__ b1,
    const float* __restrict__ w2, const float* __restrict__ b2,
    float* __restrict__ out)
{
    __shared__ float row[128];
    __shared__ float t1[128];
    __shared__ float red[2];
    int b = blockIdx.x, t = threadIdx.x;
    int n = sel[b];
    row[t] = x[(size_t)n * 128 + t];
    __syncthreads();
    float acc = b1[t];
    for (int k = 0; k < 128; ++k) acc += row[k] * w1[k * 128 + t];
    t1[t] = fmaxf(acc, 0.f);
    __syncthreads();
    float p = t1[t] * w2[t];
    for (int o = 32; o > 0; o >>= 1) p += __shfl_down(p, o, 64);
    if ((t & 63) == 0) red[t >> 6] = p;
    __syncthreads();
    if (t == 0) {
        float z = red[0] + red[1] + b2[0];
        out[b] = 1.f / (1.f + expf(-z));
    }
}

// ---------------- workspace layout (bytes) ----------------
constexpr size_t OFF_HA     = 0;                       // 201326592
constexpr size_t OFF_BN0    = 201326592;               // 4*768
constexpr size_t OFF_BN1    = OFF_BN0 + 3072;          // 4*256
constexpr size_t OFF_OLDROW = OFF_BN1 + 1024;
constexpr size_t OFF_GATE   = OFF_OLDROW + 753664;
constexpr size_t OFF_PARLOC = OFF_GATE + 753664;
constexpr size_t OFF_HB     = OFF_PARLOC + 753664;     // 48234496 (psum0/psq0 alias)
constexpr size_t OFF_XENC   = OFF_HB + 48234496;       // 4194304 (psum1/psq1 alias)
constexpr size_t OFF_BNSUM  = OFF_XENC + 4194304;
constexpr size_t OFF_BNSQ   = OFF_BNSUM + 1536;
constexpr size_t WS_NEEDED  = OFF_BNSQ + 1536;
// stage-B aliases inside hA (dead after gemm_gather):
constexpr size_t OFF_H0R  = 0;
constexpr size_t OFF_H1R  = 12582912;
constexpr size_t OFF_OUT0 = 25165824;
constexpr size_t OFF_G0   = 37748736;
constexpr size_t OFF_G1   = 41943040;
constexpr size_t OFF_OUT1 = 46137344;
constexpr size_t OFF_QI3  = 50331648;
constexpr size_t OFF_KJ3  = 50528256;
constexpr size_t OFF_LG3  = 50724864;
constexpr size_t OFF_QI1  = 51118080;
constexpr size_t OFF_KJ1  = 51183616;
constexpr size_t OFF_LG1  = 51249152;
constexpr size_t OFF_DEG  = 51380224;
constexpr size_t OFF_OFFA = 51412992;
constexpr size_t OFF_CNT  = 51446016;
constexpr size_t OFF_CSR  = 51478784;

extern "C" void kernel_launch(void* const* d_in, const int* in_sizes, int n_in,
                              void* d_out, int out_size, void* d_ws, size_t ws_size,
                              hipStream_t stream)
{
    if (n_in < 41 || ws_size < WS_NEEDED) return;

    const float* ast_x    = (const float*)d_in[0];
    const int*   ast_src  = (const int*)d_in[1];
    const int*   stmt_src = (const int*)d_in[3];
    const int*   stmt_dst = (const int*)d_in[4];
    const int*   stmt_et  = (const int*)d_in[5];
    const int*   sel      = (const int*)d_in[6];
    const float* gat0_W    = (const float*)d_in[7];
    const float* gat0_asrc = (const float*)d_in[8];
    const float* gat0_adst = (const float*)d_in[9];
    const float* gat0_b    = (const float*)d_in[10];
    const float* bn0_g     = (const float*)d_in[11];
    const float* bn0_b     = (const float*)d_in[12];
    const float* pool0_w   = (const float*)d_in[13];
    const float* gat1_W    = (const float*)d_in[14];
    const float* gat1_asrc = (const float*)d_in[15];
    const float* gat1_adst = (const float*)d_in[16];
    const float* gat1_b    = (const float*)d_in[17];
    const float* bn1_g     = (const float*)d_in[18];
    const float* bn1_b     = (const float*)d_in[19];
    const float* pool1_w   = (const float*)d_in[20];
    const float* enc_w1    = (const float*)d_in[21];
    const float* enc_b1    = (const float*)d_in[22];
    const float* enc_w2    = (const float*)d_in[23];
    const float* enc_b2    = (const float*)d_in[24];
    const float* rgat0_W   = (const float*)d_in[25];
    const float* rgat0_q   = (const float*)d_in[26];
    const float* rgat0_k   = (const float*)d_in[27];
    const float* rgat0_b   = (const float*)d_in[28];
    const float* bnc0_g    = (const float*)d_in[29];
    const float* bnc0_b    = (const float*)d_in[30];
    const float* rgat1_W   = (const float*)d_in[31];
    const float* rgat1_q   = (const float*)d_in[32];
    const float* rgat1_k   = (const float*)d_in[33];
    const float* rgat1_b   = (const float*)d_in[34];
    const float* bnc1_g    = (const float*)d_in[35];
    const float* bnc1_b    = (const float*)d_in[36];
    const float* clf_w1    = (const float*)d_in[37];
    const float* clf_b1    = (const float*)d_in[38];
    const float* clf_w2    = (const float*)d_in[39];
    const float* clf_b2    = (const float*)d_in[40];

    char* ws = (char*)d_ws;
    float* hA     = (float*)(ws + OFF_HA);
    float* ga0    = (float*)(ws + OFF_BN0);
    float* be0    = ga0 + 192;
    float* gw0    = be0 + 192;
    float* bw0    = gw0 + 192;
    float* ga1    = (float*)(ws + OFF_BN1);
    float* be1    = ga1 + 64;
    float* gw1    = be1 + 64;
    float* bw1    = gw1 + 64;
    int*   oldrow = (int*)(ws + OFF_OLDROW);
    float* gate23 = (float*)(ws + OFF_GATE);
    int*   parloc = (int*)(ws + OFF_PARLOC);
    float* hB     = (float*)(ws + OFF_HB);
    float* psum0  = (float*)(ws + OFF_HB);           // [4096][192] alias
    float* psq0   = psum0 + 192 * 4096;
    float* xenc   = (float*)(ws + OFF_XENC);
    float* psum1  = (float*)(ws + OFF_XENC);         // [8192][64] alias
    float* psq1   = psum1 + 64 * 8192;
    float* bnsum  = (float*)(ws + OFF_BNSUM);
    float* bnsq   = (float*)(ws + OFF_BNSQ);

    float* h0r  = (float*)(ws + OFF_H0R);
    float* h1r  = (float*)(ws + OFF_H1R);
    float* out0 = (float*)(ws + OFF_OUT0);
    float* g0   = (float*)(ws + OFF_G0);
    float* g1   = (float*)(ws + OFF_G1);
    float* out1 = (float*)(ws + OFF_OUT1);
    float* qi3  = (float*)(ws + OFF_QI3);
    float* kj3  = (float*)(ws + OFF_KJ3);
    float* lg3  = (float*)(ws + OFF_LG3);
    float* qi1  = (float*)(ws + OFF_QI1);
    float* kj1  = (float*)(ws + OFF_KJ1);
    float* lg1  = (float*)(ws + OFF_LG1);
    int*   deg  = (int*)(ws + OFF_DEG);
    int*   offa = (int*)(ws + OFF_OFFA);
    int*   cnt  = (int*)(ws + OFF_CNT);
    int*   csr  = (int*)(ws + OFF_CSR);

    // ---- Stage A ----
    fused_gat0<<<4096, 192, 0, stream>>>(ast_x, gat0_W, ast_src, gat0_asrc, gat0_adst,
                                         gat0_b, hA, psum0, psq0);
    bn_finalize<<<192, 256, 0, stream>>>(psum0, psq0, 4096, 192, (float)N0,
                                         bn0_g, bn0_b, pool0_w, ga0, be0, gw0, bw0);
    score_topk0<<<G, 256, 0, stream>>>(hA, ast_src, gw0, bw0, pool0_w,
                                       oldrow, gate23, parloc);
    gemm_gather<<<N1 / 64, 256, 0, stream>>>(hA, gat1_W, hB, oldrow, gate23, ga0, be0);
    gat1_att_bn<<<G, 64, 0, stream>>>(hB, parloc, gat1_asrc, gat1_adst, gat1_b,
                                      psum1, psq1);
    bn_finalize<<<64, 256, 0, stream>>>(psum1, psq1, 8192, 64, (float)N1,
                                        bn1_g, bn1_b, pool1_w, ga1, be1, gw1, bw1);
    pool1_mlp<<<G, 128, 0, stream>>>(hB, gw1, bw1, pool1_w, ga1, be1,
                                     enc_w1, enc_b1, enc_w2, enc_b2, xenc);

    // ---- Stage B ----
    gemm_nn<<<dim3(NSTMT / 64, HO3 / 64), 256, 0, stream>>>(xenc, rgat0_W, h0r, NSTMT, HO3, ENC);
    gemm_nn<<<dim3(NSTMT / 64, HO3 / 64), 256, 0, stream>>>(xenc, rgat0_W + (size_t)ENC * HO3, h1r, NSTMT, HO3, ENC);
    rgat_qk3<<<NSTMT, 256, 0, stream>>>(h0r, h1r, rgat0_q, rgat0_k, qi3, kj3);
    edge_logits3<<<EST / 256, 256, 0, stream>>>(stmt_src, stmt_dst, stmt_et, qi3, kj3, lg3);
    hipMemsetAsync(deg, 0, 32768, stream);
    hipMemsetAsync(cnt, 0, 32768, stream);
    count_deg<<<EST / 256, 256, 0, stream>>>(stmt_dst, deg);
    scan_deg<<<1, 1024, 0, stream>>>(deg, offa);
    scatter_csr<<<EST / 256, 256, 0, stream>>>(stmt_dst, offa, cnt, csr);
    rgat_agg3<<<NSTMT, 256, 0, stream>>>(h0r, h1r, offa, csr, stmt_src, stmt_et, lg3, rgat0_b, out0);
    hipMemsetAsync(bnsum, 0, 3072, stream);
    bn_stats<<<256, HO3, 0, stream>>>(out0, NSTMT, bnsum, bnsq);
    bn_apply<<<256, HO3, 0, stream>>>(out0, NSTMT, bnsum, bnsq, bnc0_g, bnc0_b);
    gemm_nn<<<dim3(NSTMT / 64, HOUT / 64), 256, 0, stream>>>(out0, rgat1_W, g0, NSTMT, HOUT, HO3);
    gemm_nn<<<dim3(NSTMT / 64, HOUT / 64), 256, 0, stream>>>(out0, rgat1_W + (size_t)HO3 * HOUT, g1, NSTMT, HOUT, HO3);
    rgat_qk1<<<NSTMT, 128, 0, stream>>>(g0, g1, rgat1_q, rgat1_k, qi1, kj1);
    edge_logits1<<<EST / 256, 256, 0, stream>>>(stmt_src, stmt_dst, stmt_et, qi1, kj1, lg1);
    rgat_agg1<<<NSTMT, 128, 0, stream>>>(g0, g1, offa, csr, stmt_src, stmt_et, lg1, rgat1_b, out1);
    hipMemsetAsync(bnsum, 0, 3072, stream);
    bn_stats<<<256, HOUT, 0, stream>>>(out1, NSTMT, bnsum, bnsq);
    bn_apply<<<256, HOUT, 0, stream>>>(out1, NSTMT, bnsum, bnsq, bnc1_g, bnc1_b);
    classifier<<<NSEL, 128, 0, stream>>>(out1, sel, clf_w1, clf_b1, clf_w2, clf_b2, (float*)d_out);
}